// Round 1
// baseline (745.744 us; speedup 1.0000x reference)
//
#include <hip/hip_runtime.h>

// FlowLayer: B=2, CIN=256, COUT=128, H=W=128, iters=24
// P = B*H*W = 32768 pixels, PC = P*128 floats per chain-state buffer (16.78 MB)
// ws layout (floats):
//   [0,2PC)   CUR0 : chainA at +0, chainB at +PC   (ping)
//   [2PC,4PC) CUR1 : ping-pong partner             (pong)
//   [4PC,6PC) S    : accumulators sa (+4PC), sb (+5PC)
//   [6PC,..)  coef (65536*32B) ; then transposed dw weights (2304+1152 floats)
// After the scan: CUR0 holds sigmoid(s1),sigmoid(s2); CUR1 reused as DW1 [P][256];
// S reused as PW1 [P][128] then DW2 [P][128].

#define PC   4194304
#define HW   16384

struct Coef { int4 o; float4 w; };

__device__ __forceinline__ float sigf(float v) { return 1.0f / (1.0f + __expf(-v)); }

// ---------------- coefficient precompute: fixed bilinear stencil per (chain, pixel)
__global__ __launch_bounds__(256) void coef_kernel(const float* __restrict__ grads,
                                                   Coef* __restrict__ coef) {
  int idx = blockIdx.x * 256 + threadIdx.x;   // 0..65535 = 2 chains * 32768 px
  int chain = idx >> 15;
  int p = idx & 32767;
  int b = p >> 14;
  int hw = p & 16383;
  int h = hw >> 7, w = hw & 127;
  float gx = grads[(size_t)(b * 2 + 0) * HW + hw];
  float gy = grads[(size_t)(b * 2 + 1) * HW + hw];
  // pixel displacement = g * (W-1)/2, g = 1.5*grads/24  ->  scale = 63.5*1.5/24
  float s = chain ? -3.96875f : 3.96875f;
  float xp = (float)w + s * gx;
  float yp = (float)h + s * gy;
  float x0f = floorf(xp), y0f = floorf(yp);
  float fx = xp - x0f, fy = yp - y0f;
  int x0 = (int)x0f, y0 = (int)y0f;
  int x1 = x0 + 1, y1 = y0 + 1;
  bool vx0 = (x0 >= 0) && (x0 <= 127);
  bool vx1 = (x1 >= 0) && (x1 <= 127);
  bool vy0 = (y0 >= 0) && (y0 <= 127);
  bool vy1 = (y1 >= 0) && (y1 <= 127);
  int x0c = min(max(x0, 0), 127), x1c = min(max(x1, 0), 127);
  int y0c = min(max(y0, 0), 127), y1c = min(max(y1, 0), 127);
  int bb = b << 14;
  Coef c;
  c.o.x = (bb + y0c * 128 + x0c) << 7;   // element offsets into [P][128] channels-last
  c.o.y = (bb + y0c * 128 + x1c) << 7;
  c.o.z = (bb + y1c * 128 + x0c) << 7;
  c.o.w = (bb + y1c * 128 + x1c) << 7;
  c.w.x = (vx0 && vy0) ? (1.f - fx) * (1.f - fy) : 0.f;
  c.w.y = (vx1 && vy0) ? fx * (1.f - fy) : 0.f;
  c.w.z = (vx0 && vy1) ? (1.f - fx) * fy : 0.f;
  c.w.w = (vx1 && vy1) ? fx * fy : 0.f;
  coef[idx] = c;
}

// ---------------- transpose depthwise weights [C][9] -> [9][C] for float4 reads
__global__ __launch_bounds__(256) void tw_kernel(const float* __restrict__ mdw,
                                                 const float* __restrict__ pdw,
                                                 float* __restrict__ wdwT,
                                                 float* __restrict__ pdwT) {
  int i = blockIdx.x * 256 + threadIdx.x;
  if (i < 2304) {
    int ch = i / 9, t = i % 9;
    wdwT[t * 256 + ch] = mdw[i];
  } else if (i < 3456) {
    int j = i - 2304;
    int ch = j / 9, t = j % 9;
    pdwT[t * 128 + ch] = pdw[j];
  }
}

// ---------------- conv1x1 (NCHW input) producing sigmoid(m1),sigmoid(m2) channels-last
// grid: (256 pixel tiles of 128) x (8 cout chunks of 32; chunks 0-3 -> w1/chainA, 4-7 -> w2/chainB)
__global__ __launch_bounds__(256) void conv1_kernel(const float* __restrict__ x,
                                                    const float* __restrict__ w1,
                                                    const float* __restrict__ w2,
                                                    float* __restrict__ mOut,
                                                    float* __restrict__ sOut) {
  __shared__ float xs[32][128];
  __shared__ float wsT[32][40];
  int tid = threadIdx.x;
  int p0 = blockIdx.x * 128;
  int c0 = blockIdx.y * 32;
  int b = p0 >> 14;
  int hw0 = p0 & 16383;
  const float* wsrc = (c0 < 128) ? (w1 + (size_t)c0 * 256) : (w2 + (size_t)(c0 - 128) * 256);
  const float* xbase = x + (size_t)b * 256 * HW + hw0;
  int pxg = tid & 31, cog = tid >> 5;
  float acc[4][4] = {};
  for (int ci0 = 0; ci0 < 256; ci0 += 32) {
    int col = tid & 127;
    int r0 = tid >> 7;
#pragma unroll
    for (int r = 0; r < 16; r++)
      xs[r0 + r * 2][col] = xbase[(size_t)(ci0 + r0 + r * 2) * HW + col];
    {
      int co = tid >> 3, c4 = (tid & 7) * 4;
      float4 v = *(const float4*)(wsrc + (size_t)co * 256 + ci0 + c4);
      wsT[c4 + 0][co] = v.x; wsT[c4 + 1][co] = v.y; wsT[c4 + 2][co] = v.z; wsT[c4 + 3][co] = v.w;
    }
    __syncthreads();
#pragma unroll
    for (int ci = 0; ci < 32; ci++) {
      float4 xv = *(const float4*)&xs[ci][pxg * 4];
      float4 wv = *(const float4*)&wsT[ci][cog * 4];
      float xa[4] = {xv.x, xv.y, xv.z, xv.w};
      float wa[4] = {wv.x, wv.y, wv.z, wv.w};
#pragma unroll
      for (int i = 0; i < 4; i++)
#pragma unroll
        for (int j = 0; j < 4; j++)
          acc[i][j] = fmaf(xa[i], wa[j], acc[i][j]);
    }
    __syncthreads();
  }
  size_t base = (c0 < 128) ? 0 : (size_t)PC;
  int col0 = (c0 & 127) + cog * 4;
#pragma unroll
  for (int i = 0; i < 4; i++) {
    float4 r;
    r.x = sigf(acc[i][0]); r.y = sigf(acc[i][1]); r.z = sigf(acc[i][2]); r.w = sigf(acc[i][3]);
    size_t off = base + (size_t)(p0 + pxg * 4 + i) * 128 + col0;
    *(float4*)(mOut + off) = r;   // chain state init
    *(float4*)(sOut + off) = r;   // accumulator init (carry starts at m)
  }
}

// ---------------- one scan step for BOTH chains: out = S*in ; s += out
// FINAL step writes sigmoid(s + out) into outb instead (feeds the merge stage).
template <bool FINAL>
__global__ __launch_bounds__(256) void step_kernel(const float* __restrict__ inb,
                                                   float* __restrict__ outb,
                                                   float* __restrict__ sb,
                                                   const Coef* __restrict__ coef) {
  int tid = threadIdx.x;
  int slot = blockIdx.x * 8 + (tid >> 5);   // 0..65535
  int chain = slot >> 15;
  int p = slot & 32767;
  size_t cb = (size_t)chain * PC;
  Coef c = coef[slot];
  int ch = (tid & 31) << 2;
  const float* in_ = inb + cb;
  float4 v00 = *(const float4*)(in_ + c.o.x + ch);
  float4 v10 = *(const float4*)(in_ + c.o.y + ch);
  float4 v01 = *(const float4*)(in_ + c.o.z + ch);
  float4 v11 = *(const float4*)(in_ + c.o.w + ch);
  float4 r;
  r.x = c.w.x * v00.x + c.w.y * v10.x + c.w.z * v01.x + c.w.w * v11.x;
  r.y = c.w.x * v00.y + c.w.y * v10.y + c.w.z * v01.y + c.w.w * v11.y;
  r.z = c.w.x * v00.z + c.w.y * v10.z + c.w.z * v01.z + c.w.w * v11.z;
  r.w = c.w.x * v00.w + c.w.y * v10.w + c.w.z * v01.w + c.w.w * v11.w;
  size_t ob = cb + (size_t)p * 128 + ch;
  if (FINAL) {
    float4 sv = *(const float4*)(sb + ob);
    float4 q;
    q.x = sigf(sv.x + r.x); q.y = sigf(sv.y + r.y);
    q.z = sigf(sv.z + r.z); q.w = sigf(sv.w + r.w);
    *(float4*)(outb + ob) = q;
  } else {
    *(float4*)(outb + ob) = r;
    float4 sv = *(const float4*)(sb + ob);
    sv.x += r.x; sv.y += r.y; sv.z += r.z; sv.w += r.w;
    *(float4*)(sb + ob) = sv;
  }
}

// ---------------- depthwise 3x3, zero pad. C=256 reads two PC-sized halves; C=128 one buffer.
template <int C>
__global__ __launch_bounds__(256) void dw_kernel(const float* __restrict__ in,
                                                 const float* __restrict__ wT,
                                                 float* __restrict__ out) {
  int tid = threadIdx.x;
  constexpr int TPP = C / 4;        // threads per pixel
  constexpr int PPB = 256 / TPP;    // pixels per block
  int slot = blockIdx.x * PPB + tid / TPP;
  int ch = (tid % TPP) * 4;
  int b = slot >> 14, h = (slot >> 7) & 127, w = slot & 127;
  const float* src;
  int choff;
  if (C == 256) { src = in + ((ch < 128) ? 0 : (size_t)PC); choff = ch & 127; }
  else          { src = in; choff = ch; }
  float4 acc = {0.f, 0.f, 0.f, 0.f};
#pragma unroll
  for (int t = 0; t < 9; t++) {
    int dy = t / 3 - 1, dx = t % 3 - 1;
    int yy = h + dy, xx = w + dx;
    if (yy < 0 || yy > 127 || xx < 0 || xx > 127) continue;
    int q = (b << 14) + yy * 128 + xx;
    float4 v = *(const float4*)(src + (size_t)q * 128 + choff);
    float4 wv = *(const float4*)(wT + t * C + ch);
    acc.x = fmaf(wv.x, v.x, acc.x);
    acc.y = fmaf(wv.y, v.y, acc.y);
    acc.z = fmaf(wv.z, v.z, acc.z);
    acc.w = fmaf(wv.w, v.w, acc.w);
  }
  *(float4*)(out + (size_t)slot * C + ch) = acc;
}

// ---------------- pointwise 1x1 (channels-last in) + bias; optionally write NCHW
template <int CIN, bool NCHW>
__global__ __launch_bounds__(256) void pw_kernel(const float* __restrict__ in,
                                                 const float* __restrict__ w,
                                                 const float* __restrict__ bias,
                                                 float* __restrict__ out) {
  __shared__ float xsT[32][132];
  __shared__ float wsT[32][40];
  int tid = threadIdx.x;
  int p0 = blockIdx.x * 128;
  int co0 = blockIdx.y * 32;
  int pxg = tid & 31, cog = tid >> 5;
  float acc[4][4] = {};
  for (int ci0 = 0; ci0 < CIN; ci0 += 32) {
#pragma unroll
    for (int pass = 0; pass < 4; pass++) {
      int idx = tid + pass * 256;         // 0..1023
      int px = idx >> 3, c4 = (idx & 7) * 4;
      float4 v = *(const float4*)(in + (size_t)(p0 + px) * CIN + ci0 + c4);
      xsT[c4 + 0][px] = v.x; xsT[c4 + 1][px] = v.y; xsT[c4 + 2][px] = v.z; xsT[c4 + 3][px] = v.w;
    }
    {
      int co = tid >> 3, c4 = (tid & 7) * 4;
      float4 v = *(const float4*)(w + (size_t)(co0 + co) * CIN + ci0 + c4);
      wsT[c4 + 0][co] = v.x; wsT[c4 + 1][co] = v.y; wsT[c4 + 2][co] = v.z; wsT[c4 + 3][co] = v.w;
    }
    __syncthreads();
#pragma unroll
    for (int ci = 0; ci < 32; ci++) {
      float4 xv = *(const float4*)&xsT[ci][pxg * 4];
      float4 wv = *(const float4*)&wsT[ci][cog * 4];
      float xa[4] = {xv.x, xv.y, xv.z, xv.w};
      float wa[4] = {wv.x, wv.y, wv.z, wv.w};
#pragma unroll
      for (int i = 0; i < 4; i++)
#pragma unroll
        for (int j = 0; j < 4; j++)
          acc[i][j] = fmaf(xa[i], wa[j], acc[i][j]);
    }
    __syncthreads();
  }
  float4 bv = *(const float4*)(bias + co0 + cog * 4);
  float ba[4] = {bv.x, bv.y, bv.z, bv.w};
  if (NCHW) {
    int b = p0 >> 14, hw0 = p0 & 16383;
#pragma unroll
    for (int j = 0; j < 4; j++) {
      int co = co0 + cog * 4 + j;
#pragma unroll
      for (int i = 0; i < 4; i++)
        out[(size_t)(b * 128 + co) * HW + hw0 + pxg * 4 + i] = acc[i][j] + ba[j];
    }
  } else {
#pragma unroll
    for (int i = 0; i < 4; i++) {
      float4 r = {acc[i][0] + ba[0], acc[i][1] + ba[1], acc[i][2] + ba[2], acc[i][3] + ba[3]};
      *(float4*)(out + (size_t)(p0 + pxg * 4 + i) * 128 + co0 + cog * 4) = r;
    }
  }
}

extern "C" void kernel_launch(void* const* d_in, const int* in_sizes, int n_in,
                              void* d_out, int out_size, void* d_ws, size_t ws_size,
                              hipStream_t stream) {
  const float* x     = (const float*)d_in[0];
  const float* grads = (const float*)d_in[1];
  const float* w1    = (const float*)d_in[2];
  const float* w2    = (const float*)d_in[3];
  const float* mdw   = (const float*)d_in[4];
  const float* mpw   = (const float*)d_in[5];
  const float* mb    = (const float*)d_in[6];
  const float* pdw   = (const float*)d_in[7];
  const float* ppw   = (const float*)d_in[8];
  const float* pb    = (const float*)d_in[9];
  float* out = (float*)d_out;
  float* wsf = (float*)d_ws;

  float* CUR0 = wsf;
  float* CUR1 = wsf + 2 * (size_t)PC;
  float* S    = wsf + 4 * (size_t)PC;
  Coef* coef  = (Coef*)(wsf + 6 * (size_t)PC);
  float* wdwT = wsf + 6 * (size_t)PC + 524288;
  float* pdwT = wdwT + 2304;

  coef_kernel<<<256, 256, 0, stream>>>(grads, coef);
  tw_kernel<<<14, 256, 0, stream>>>(mdw, pdw, wdwT, pdwT);
  conv1_kernel<<<dim3(256, 8), 256, 0, stream>>>(x, w1, w2, CUR0, S);

  for (int k = 0; k < 24; k++) {
    const float* in_ = (k & 1) ? CUR1 : CUR0;
    float* out_      = (k & 1) ? CUR0 : CUR1;
    if (k < 23) step_kernel<false><<<8192, 256, 0, stream>>>(in_, out_, S, coef);
    else        step_kernel<true ><<<8192, 256, 0, stream>>>(in_, out_, S, coef);
  }
  // CUR0 now holds sigmoid(s1) (chain A, +0) and sigmoid(s2) (chain B, +PC)
  float* DW1 = CUR1;      // [P][256]
  float* PW1 = S;         // [P][128]
  float* DW2 = S + PC;    // [P][128]
  dw_kernel<256><<<8192, 256, 0, stream>>>(CUR0, wdwT, DW1);
  pw_kernel<256, false><<<dim3(256, 4), 256, 0, stream>>>(DW1, mpw, mb, PW1);
  dw_kernel<128><<<4096, 256, 0, stream>>>(PW1, pdwT, DW2);
  pw_kernel<128, true ><<<dim3(256, 4), 256, 0, stream>>>(DW2, ppw, pb, out);
}

// Round 3
// 603.281 us; speedup vs baseline: 1.2361x; 1.2361x over previous
//
#include <hip/hip_runtime.h>
#include <hip/hip_fp16.h>

// FlowLayer: B=2, CIN=256, COUT=128, H=W=128, iters=24
// P = B*H*W = 32768 pixels; PC = P*128 = 4194304 elements per chain buffer.
// All intermediate state is fp16 (values bounded: state in [0,1], acc in [0,24]).
// ws layout (bytes):
//   [0,16MB)    BUF0 (fp16, 2 chains)  — m init; final sigmoid(s) lands here
//   [16,32MB)   BUF1 (fp16)            — ping-pong partner; reused as DW1 [P][256]
//   [32,48MB)   ACC  (fp16)            — running sum; reused as PW1/DW2
//   [48MB,..)   coef (65536*32B), then transposed dw weights (f32)

#define PC 4194304
#define HW 16384

struct Coef { int4 o; float4 w; };
struct alignas(16) H8 { __half2 h[4]; };
struct alignas(8)  H4 { __half2 h[2]; };

__device__ __forceinline__ float sigf(float v) { return 1.0f / (1.0f + __expf(-v)); }

__device__ __forceinline__ void h8f(const H8& v, float* f) {
#pragma unroll
  for (int i = 0; i < 4; i++) { float2 t = __half22float2(v.h[i]); f[2*i] = t.x; f[2*i+1] = t.y; }
}
__device__ __forceinline__ H8 f8h(const float* f) {
  H8 r;
#pragma unroll
  for (int i = 0; i < 4; i++) r.h[i] = __floats2half2_rn(f[2*i], f[2*i+1]);
  return r;
}

// ---------------- coefficient precompute: fixed bilinear stencil per (chain, pixel)
__global__ __launch_bounds__(256) void coef_kernel(const float* __restrict__ grads,
                                                   Coef* __restrict__ coef) {
  int idx = blockIdx.x * 256 + threadIdx.x;   // 0..65535 = 2 chains * 32768 px
  int chain = idx >> 15;
  int p = idx & 32767;
  int b = p >> 14;
  int hw = p & 16383;
  int h = hw >> 7, w = hw & 127;
  float gx = grads[(size_t)(b * 2 + 0) * HW + hw];
  float gy = grads[(size_t)(b * 2 + 1) * HW + hw];
  // pixel displacement = g*(W-1)/2, g = 1.5*grads/24 -> scale = 63.5*1.5/24
  float s = chain ? -3.96875f : 3.96875f;
  float xp = (float)w + s * gx;
  float yp = (float)h + s * gy;
  float x0f = floorf(xp), y0f = floorf(yp);
  float fx = xp - x0f, fy = yp - y0f;
  int x0 = (int)x0f, y0 = (int)y0f;
  int x1 = x0 + 1, y1 = y0 + 1;
  bool vx0 = (x0 >= 0) && (x0 <= 127);
  bool vx1 = (x1 >= 0) && (x1 <= 127);
  bool vy0 = (y0 >= 0) && (y0 <= 127);
  bool vy1 = (y1 >= 0) && (y1 <= 127);
  int x0c = min(max(x0, 0), 127), x1c = min(max(x1, 0), 127);
  int y0c = min(max(y0, 0), 127), y1c = min(max(y1, 0), 127);
  int bb = b << 14;
  Coef c;
  c.o.x = (bb + y0c * 128 + x0c) << 7;   // element offsets into [P][128] channels-last
  c.o.y = (bb + y0c * 128 + x1c) << 7;
  c.o.z = (bb + y1c * 128 + x0c) << 7;
  c.o.w = (bb + y1c * 128 + x1c) << 7;
  c.w.x = (vx0 && vy0) ? (1.f - fx) * (1.f - fy) : 0.f;
  c.w.y = (vx1 && vy0) ? fx * (1.f - fy) : 0.f;
  c.w.z = (vx0 && vy1) ? (1.f - fx) * fy : 0.f;
  c.w.w = (vx1 && vy1) ? fx * fy : 0.f;
  coef[idx] = c;
}

// ---------------- transpose depthwise weights [C][9] -> [9][C]
__global__ __launch_bounds__(256) void tw_kernel(const float* __restrict__ mdw,
                                                 const float* __restrict__ pdw,
                                                 float* __restrict__ wdwT,
                                                 float* __restrict__ pdwT) {
  int i = blockIdx.x * 256 + threadIdx.x;
  if (i < 2304) {
    int ch = i / 9, t = i % 9;
    wdwT[t * 256 + ch] = mdw[i];
  } else if (i < 3456) {
    int j = i - 2304;
    int ch = j / 9, t = j % 9;
    pdwT[t * 128 + ch] = pdw[j];
  }
}

// ---------------- conv1x1 (NCHW f32 in) -> sigmoid -> fp16 channels-last (state + acc init)
__global__ __launch_bounds__(256) void conv1_kernel(const float* __restrict__ x,
                                                    const float* __restrict__ w1,
                                                    const float* __restrict__ w2,
                                                    __half* __restrict__ mOut,
                                                    __half* __restrict__ accOut) {
  __shared__ float xs[32][128];
  __shared__ float wsT[32][40];
  int tid = threadIdx.x;
  int p0 = blockIdx.x * 128;
  int c0 = blockIdx.y * 32;
  int b = p0 >> 14;
  int hw0 = p0 & 16383;
  const float* wsrc = (c0 < 128) ? (w1 + (size_t)c0 * 256) : (w2 + (size_t)(c0 - 128) * 256);
  const float* xbase = x + (size_t)b * 256 * HW + hw0;
  int pxg = tid & 31, cog = tid >> 5;
  float acc[4][4] = {};
  for (int ci0 = 0; ci0 < 256; ci0 += 32) {
    int col = tid & 127;
    int r0 = tid >> 7;
#pragma unroll
    for (int r = 0; r < 16; r++)
      xs[r0 + r * 2][col] = xbase[(size_t)(ci0 + r0 + r * 2) * HW + col];
    {
      int co = tid >> 3, c4 = (tid & 7) * 4;
      float4 v = *(const float4*)(wsrc + (size_t)co * 256 + ci0 + c4);
      wsT[c4 + 0][co] = v.x; wsT[c4 + 1][co] = v.y; wsT[c4 + 2][co] = v.z; wsT[c4 + 3][co] = v.w;
    }
    __syncthreads();
#pragma unroll
    for (int ci = 0; ci < 32; ci++) {
      float4 xv = *(const float4*)&xs[ci][pxg * 4];
      float4 wv = *(const float4*)&wsT[ci][cog * 4];
      float xa[4] = {xv.x, xv.y, xv.z, xv.w};
      float wa[4] = {wv.x, wv.y, wv.z, wv.w};
#pragma unroll
      for (int i = 0; i < 4; i++)
#pragma unroll
        for (int j = 0; j < 4; j++)
          acc[i][j] = fmaf(xa[i], wa[j], acc[i][j]);
    }
    __syncthreads();
  }
  size_t base = (c0 < 128) ? 0 : (size_t)PC;
  int col0 = (c0 & 127) + cog * 4;
#pragma unroll
  for (int i = 0; i < 4; i++) {
    H4 hv;
    hv.h[0] = __floats2half2_rn(sigf(acc[i][0]), sigf(acc[i][1]));
    hv.h[1] = __floats2half2_rn(sigf(acc[i][2]), sigf(acc[i][3]));
    size_t off = base + (size_t)(p0 + pxg * 4 + i) * 128 + col0;
    *(H4*)(mOut + off) = hv;
    *(H4*)(accOut + off) = hv;
  }
}

// ---------------- one scan step, both chains, fp16: out = S*in ; acc += out
// FINAL step writes sigmoid(acc + out) into outb (feeds merge stage).
template <bool FINAL>
__global__ __launch_bounds__(256) void step_kernel(const __half* __restrict__ inb,
                                                   __half* __restrict__ outb,
                                                   __half* __restrict__ accb,
                                                   const Coef* __restrict__ coef) {
  int gtid = blockIdx.x * 256 + threadIdx.x;   // 0..262143
  int slot = gtid >> 2;                        // chain*32768 + pixel
  int sub = gtid & 3;
  int chain = slot >> 15;
  int p = slot & 32767;
  size_t cb = (size_t)chain * PC;
  Coef c = coef[slot];
  const __half* pin = inb + cb;
  size_t own = cb + ((size_t)p << 7) + sub * 8;
#pragma unroll
  for (int j = 0; j < 4; j++) {
    int cho = sub * 8 + j * 32;
    float v00[8], v10[8], v01[8], v11[8], r[8], af[8];
    h8f(*(const H8*)(pin + c.o.x + cho), v00);
    h8f(*(const H8*)(pin + c.o.y + cho), v10);
    h8f(*(const H8*)(pin + c.o.z + cho), v01);
    h8f(*(const H8*)(pin + c.o.w + cho), v11);
    size_t oj = own + (size_t)j * 32;
#pragma unroll
    for (int i = 0; i < 8; i++)
      r[i] = c.w.x * v00[i] + c.w.y * v10[i] + c.w.z * v01[i] + c.w.w * v11[i];
    h8f(*(const H8*)(accb + oj), af);
    if (FINAL) {
#pragma unroll
      for (int i = 0; i < 8; i++) r[i] = sigf(af[i] + r[i]);
      *(H8*)(outb + oj) = f8h(r);
    } else {
#pragma unroll
      for (int i = 0; i < 8; i++) af[i] += r[i];
      *(H8*)(outb + oj) = f8h(r);
      *(H8*)(accb + oj) = f8h(af);
    }
  }
}

// ---------------- depthwise 3x3, zero pad, fp16 in/out, f32 weights/accum
template <int C>
__global__ __launch_bounds__(256) void dw_kernel(const __half* __restrict__ in,
                                                 const float* __restrict__ wT,
                                                 __half* __restrict__ out) {
  int tid = threadIdx.x;
  constexpr int TPP = C / 8;        // threads per pixel (8 ch each)
  constexpr int PPB = 256 / TPP;    // pixels per block
  int slot = blockIdx.x * PPB + tid / TPP;
  int ch = (tid % TPP) * 8;
  int b = slot >> 14, h = (slot >> 7) & 127, w = slot & 127;
  const __half* src;
  int choff;
  if (C == 256) { src = in + ((ch < 128) ? 0 : (size_t)PC); choff = ch & 127; }
  else          { src = in; choff = ch; }
  float acc[8] = {};
#pragma unroll
  for (int t = 0; t < 9; t++) {
    int dy = t / 3 - 1, dx = t % 3 - 1;
    int yy = h + dy, xx = w + dx;
    if (yy < 0 || yy > 127 || xx < 0 || xx > 127) continue;
    int q = (b << 14) + yy * 128 + xx;
    float v[8];
    h8f(*(const H8*)(src + (size_t)q * 128 + choff), v);
    float4 wa = *(const float4*)(wT + t * C + ch);
    float4 wb = *(const float4*)(wT + t * C + ch + 4);
    acc[0] = fmaf(wa.x, v[0], acc[0]);
    acc[1] = fmaf(wa.y, v[1], acc[1]);
    acc[2] = fmaf(wa.z, v[2], acc[2]);
    acc[3] = fmaf(wa.w, v[3], acc[3]);
    acc[4] = fmaf(wb.x, v[4], acc[4]);
    acc[5] = fmaf(wb.y, v[5], acc[5]);
    acc[6] = fmaf(wb.z, v[6], acc[6]);
    acc[7] = fmaf(wb.w, v[7], acc[7]);
  }
  *(H8*)(out + (size_t)slot * C + ch) = f8h(acc);
}

// ---------------- pointwise 1x1 (fp16 channels-last in, f32 weights) + bias
template <int CIN, bool NCHW>
__global__ __launch_bounds__(256) void pw_kernel(const __half* __restrict__ in,
                                                 const float* __restrict__ w,
                                                 const float* __restrict__ bias,
                                                 void* __restrict__ outv) {
  __shared__ float xsT[32][132];
  __shared__ float wsT[32][40];
  int tid = threadIdx.x;
  int p0 = blockIdx.x * 128;
  int co0 = blockIdx.y * 32;
  int pxg = tid & 31, cog = tid >> 5;
  float acc[4][4] = {};
  for (int ci0 = 0; ci0 < CIN; ci0 += 32) {
#pragma unroll
    for (int pass = 0; pass < 2; pass++) {
      int idx = tid + pass * 256;          // 0..511
      int px = idx >> 2, c8 = (idx & 3) * 8;
      float f[8];
      h8f(*(const H8*)(in + (size_t)(p0 + px) * CIN + ci0 + c8), f);
#pragma unroll
      for (int i = 0; i < 8; i++) xsT[c8 + i][px] = f[i];
    }
    {
      int co = tid >> 3, c4 = (tid & 7) * 4;
      float4 v = *(const float4*)(w + (size_t)(co0 + co) * CIN + ci0 + c4);
      wsT[c4 + 0][co] = v.x; wsT[c4 + 1][co] = v.y; wsT[c4 + 2][co] = v.z; wsT[c4 + 3][co] = v.w;
    }
    __syncthreads();
#pragma unroll
    for (int ci = 0; ci < 32; ci++) {
      float4 xv = *(const float4*)&xsT[ci][pxg * 4];
      float4 wv = *(const float4*)&wsT[ci][cog * 4];
      float xa[4] = {xv.x, xv.y, xv.z, xv.w};
      float wa[4] = {wv.x, wv.y, wv.z, wv.w};
#pragma unroll
      for (int i = 0; i < 4; i++)
#pragma unroll
        for (int j = 0; j < 4; j++)
          acc[i][j] = fmaf(xa[i], wa[j], acc[i][j]);
    }
    __syncthreads();
  }
  float4 bv = *(const float4*)(bias + co0 + cog * 4);
  float ba[4] = {bv.x, bv.y, bv.z, bv.w};
  if (NCHW) {
    float* out = (float*)outv;
    int b = p0 >> 14, hw0 = p0 & 16383;
#pragma unroll
    for (int j = 0; j < 4; j++) {
      int co = co0 + cog * 4 + j;
#pragma unroll
      for (int i = 0; i < 4; i++)
        out[(size_t)(b * 128 + co) * HW + hw0 + pxg * 4 + i] = acc[i][j] + ba[j];
    }
  } else {
    __half* out = (__half*)outv;
#pragma unroll
    for (int i = 0; i < 4; i++) {
      H4 hv;
      hv.h[0] = __floats2half2_rn(acc[i][0] + ba[0], acc[i][1] + ba[1]);
      hv.h[1] = __floats2half2_rn(acc[i][2] + ba[2], acc[i][3] + ba[3]);
      *(H4*)(out + (size_t)(p0 + pxg * 4 + i) * 128 + co0 + cog * 4) = hv;
    }
  }
}

extern "C" void kernel_launch(void* const* d_in, const int* in_sizes, int n_in,
                              void* d_out, int out_size, void* d_ws, size_t ws_size,
                              hipStream_t stream) {
  const float* x     = (const float*)d_in[0];
  const float* grads = (const float*)d_in[1];
  const float* w1    = (const float*)d_in[2];
  const float* w2    = (const float*)d_in[3];
  const float* mdw   = (const float*)d_in[4];
  const float* mpw   = (const float*)d_in[5];
  const float* mb    = (const float*)d_in[6];
  const float* pdw   = (const float*)d_in[7];
  const float* ppw   = (const float*)d_in[8];
  const float* pb    = (const float*)d_in[9];
  float* out = (float*)d_out;
  char* wsb = (char*)d_ws;

  __half* BUF0 = (__half*)wsb;                                  // 2PC halves = 16 MB
  __half* BUF1 = (__half*)(wsb + (size_t)16777216);
  __half* ACC  = (__half*)(wsb + (size_t)33554432);
  Coef*  coef  = (Coef*)(wsb + (size_t)50331648);               // 2 MB
  float* wdwT  = (float*)(wsb + (size_t)52428800);
  float* pdwT  = wdwT + 2304;

  coef_kernel<<<256, 256, 0, stream>>>(grads, coef);
  tw_kernel<<<14, 256, 0, stream>>>(mdw, pdw, wdwT, pdwT);
  conv1_kernel<<<dim3(256, 8), 256, 0, stream>>>(x, w1, w2, BUF0, ACC);

  for (int k = 0; k < 23; k++) {
    const __half* in_ = (k & 1) ? BUF1 : BUF0;
    __half* out_      = (k & 1) ? BUF0 : BUF1;
    step_kernel<false><<<1024, 256, 0, stream>>>(in_, out_, ACC, coef);
  }
  // k=23: in = BUF1, write sigmoid(acc + S*in) to BUF0
  step_kernel<true><<<1024, 256, 0, stream>>>(BUF1, BUF0, ACC, coef);

  // BUF0 = sigmoid(s1) chain A (+0), sigmoid(s2) chain B (+PC), fp16 channels-last
  __half* DW1 = BUF1;        // [P][256] fp16
  __half* PW1 = ACC;         // [P][128] fp16
  __half* DW2 = ACC + PC;    // [P][128] fp16
  dw_kernel<256><<<4096, 256, 0, stream>>>(BUF0, wdwT, DW1);
  pw_kernel<256, false><<<dim3(256, 4), 256, 0, stream>>>(DW1, mpw, mb, (void*)PW1);
  dw_kernel<128><<<2048, 256, 0, stream>>>(PW1, pdwT, DW2);
  pw_kernel<128, true ><<<dim3(256, 4), 256, 0, stream>>>(DW2, ppw, pb, (void*)out);
}

// Round 4
// 333.031 us; speedup vs baseline: 2.2393x; 1.8115x over previous
//
#include <hip/hip_runtime.h>
#include <hip/hip_fp16.h>

// FlowLayer: B=2, CIN=256, COUT=128, H=W=128, iters=24 (= 12 fused pairs)
// P = 32768 pixels; PC = P*128 elements per chain buffer (fp16 -> 8.4 MB each).
// ws layout (bytes):
//   [0,16M)      BUF0 (fp16, 2 chains)  - m init; final sigmoid(s) lands here
//   [16M,32M)    BUF1 (fp16)            - ping-pong; reused as DW1 [P][256]
//   [32M,48M)    ACC  (fp16)            - running sum; reused as PW1/DW2
//   [48M,58.3M)  COEF2 (65536 x 160B composed stencils)
//   then WT16 (256x256 f16), wdwT, pdwT

#define PC 4194304
#define HW 16384

struct Coef2 {            // 160 B = 10 uint4
  int4 oa;                // own 4 tap element-offsets (pixel<<7, bb included)
  float4 wa;              // own 4 masked weights
  int4 oc0, oc1, oc2, oc3;     // composed 16 offsets
  float4 wc0, wc1, wc2, wc3;   // composed 16 weights (w_i * w_ij)
};

struct alignas(16) H8 { __half2 h[4]; };
struct alignas(8)  H4 { __half2 h[2]; };
typedef _Float16 f16x8 __attribute__((ext_vector_type(8)));
typedef float f32x4 __attribute__((ext_vector_type(4)));

__device__ __forceinline__ float sigf(float v) { return 1.0f / (1.0f + __expf(-v)); }

__device__ __forceinline__ void h8f(const H8& v, float* f) {
#pragma unroll
  for (int i = 0; i < 4; i++) { float2 t = __half22float2(v.h[i]); f[2*i] = t.x; f[2*i+1] = t.y; }
}
__device__ __forceinline__ H8 f8h(const float* f) {
  H8 r;
#pragma unroll
  for (int i = 0; i < 4; i++) r.h[i] = __floats2half2_rn(f[2*i], f[2*i+1]);
  return r;
}

// ---------------- per-pixel bilinear stencil (pixel indices + masked weights)
__device__ __forceinline__ void stencil(const float* __restrict__ g, float sgn, int pix,
                                        int4& op, float4& wt) {
  int b = pix >> 14, hw = pix & 16383;
  int h = hw >> 7, w = hw & 127;
  float gx = g[(size_t)(b * 2 + 0) * HW + hw];
  float gy = g[(size_t)(b * 2 + 1) * HW + hw];
  float xp = (float)w + sgn * gx;
  float yp = (float)h + sgn * gy;
  float x0f = floorf(xp), y0f = floorf(yp);
  float fx = xp - x0f, fy = yp - y0f;
  int x0 = (int)x0f, y0 = (int)y0f;
  int x1 = x0 + 1, y1 = y0 + 1;
  bool vx0 = (x0 >= 0) && (x0 <= 127);
  bool vx1 = (x1 >= 0) && (x1 <= 127);
  bool vy0 = (y0 >= 0) && (y0 <= 127);
  bool vy1 = (y1 >= 0) && (y1 <= 127);
  int x0c = min(max(x0, 0), 127), x1c = min(max(x1, 0), 127);
  int y0c = min(max(y0, 0), 127), y1c = min(max(y1, 0), 127);
  int bb = b << 14;
  op.x = bb + y0c * 128 + x0c;
  op.y = bb + y0c * 128 + x1c;
  op.z = bb + y1c * 128 + x0c;
  op.w = bb + y1c * 128 + x1c;
  wt.x = (vx0 && vy0) ? (1.f - fx) * (1.f - fy) : 0.f;
  wt.y = (vx1 && vy0) ? fx * (1.f - fy) : 0.f;
  wt.z = (vx0 && vy1) ? (1.f - fx) * fy : 0.f;
  wt.w = (vx1 && vy1) ? fx * fy : 0.f;
}

__device__ __forceinline__ int4 shl7(int4 v) {
  return make_int4(v.x << 7, v.y << 7, v.z << 7, v.w << 7);
}
__device__ __forceinline__ float4 scale4(float4 v, float s) {
  return make_float4(v.x * s, v.y * s, v.z * s, v.w * s);
}

// ---------------- composed 2-step stencil precompute
__global__ __launch_bounds__(256) void coef2_kernel(const float* __restrict__ grads,
                                                    Coef2* __restrict__ c2) {
  int idx = blockIdx.x * 256 + threadIdx.x;   // 0..65535
  int chain = idx >> 15;
  int p = idx & 32767;
  float sgn = chain ? -3.96875f : 3.96875f;   // 63.5*1.5/24
  Coef2 c;
  int4 op; float4 ow;
  stencil(grads, sgn, p, op, ow);
  c.oa = shl7(op);
  c.wa = ow;
  int4 o2; float4 nw;
  stencil(grads, sgn, op.x, o2, nw); c.oc0 = shl7(o2); c.wc0 = scale4(nw, ow.x);
  stencil(grads, sgn, op.y, o2, nw); c.oc1 = shl7(o2); c.wc1 = scale4(nw, ow.y);
  stencil(grads, sgn, op.z, o2, nw); c.oc2 = shl7(o2); c.wc2 = scale4(nw, ow.z);
  stencil(grads, sgn, op.w, o2, nw); c.oc3 = shl7(o2); c.wc3 = scale4(nw, ow.w);
  c2[idx] = c;
}

// ---------------- weight prep: f16 GEMM weights [256co][256ci] + transposed dw weights
__global__ __launch_bounds__(256) void tw_kernel(const float* __restrict__ mdw,
                                                 const float* __restrict__ pdw,
                                                 const float* __restrict__ w1,
                                                 const float* __restrict__ w2,
                                                 float* __restrict__ wdwT,
                                                 float* __restrict__ pdwT,
                                                 __half* __restrict__ wT16) {
  int i = blockIdx.x * 256 + threadIdx.x;
  if (i < 65536) {
    int co = i >> 8, ci = i & 255;
    float v = (co < 128) ? w1[co * 256 + ci] : w2[(size_t)(co - 128) * 256 + ci];
    wT16[i] = __float2half(v);
  } else if (i < 65536 + 2304) {
    int j = i - 65536;
    int ch = j / 9, t = j % 9;
    wdwT[t * 256 + ch] = mdw[j];
  } else if (i < 65536 + 3456) {
    int j = i - 65536 - 2304;
    int ch = j / 9, t = j % 9;
    pdwT[t * 128 + ch] = pdw[j];
  }
}

// ---------------- conv1x1 via f16 MFMA: [32768px] x [256ci] @ [256ci]x[256co]
// block = 64 px x 256 co, 4 waves (wave w -> co w*64..w*64+64). sigmoid -> fp16 NHWC.
__global__ __launch_bounds__(256) void conv1_kernel(const float* __restrict__ x,
                                                    const __half* __restrict__ wT16,
                                                    __half* __restrict__ mOut) {
  __shared__ __align__(16) char As[4096];    // [64px][32ci] f16, XOR-swizzled
  __shared__ __align__(16) char Bs[16384];   // [256co][32ci] f16, XOR-swizzled
  int tid = threadIdx.x;
  int p0 = blockIdx.x * 64;
  int b = p0 >> 14;
  int hw0 = p0 & 16383;
  int wv = tid >> 6, ln = tid & 63;
  int hi = ln >> 4, lo = ln & 15;
  f32x4 acc[4][4] = {};
  const float* xb = x + (size_t)b * 256 * HW + hw0;
  int apx = tid & 63, ac8 = (tid >> 6) * 8;
  int abyte = (apx * 64 + ac8 * 2) ^ ((apx & 3) << 4);
  for (int k = 0; k < 256; k += 32) {
    f16x8 av;
#pragma unroll
    for (int j = 0; j < 8; j++) av[j] = (_Float16)xb[(size_t)(k + ac8 + j) * HW + apx];
    if (k) __syncthreads();          // prior iter's frag reads done before overwrite
    *(f16x8*)(As + abyte) = av;
    {
      const __half* src = wT16 + (size_t)tid * 256 + k;
#pragma unroll
      for (int s = 0; s < 4; s++) {
        f16x8 bv = *(const f16x8*)(src + s * 8);
        int byte = (tid * 64 + s * 16) ^ ((tid & 3) << 4);
        *(f16x8*)(Bs + byte) = bv;
      }
    }
    __syncthreads();
    f16x8 aF[4], bF[4];
#pragma unroll
    for (int m = 0; m < 4; m++) {
      int px = m * 16 + lo;
      int byte = (px * 64 + hi * 16) ^ ((px & 3) << 4);
      aF[m] = *(const f16x8*)(As + byte);
    }
#pragma unroll
    for (int n = 0; n < 4; n++) {
      int co = wv * 64 + n * 16 + lo;
      int byte = (co * 64 + hi * 16) ^ ((co & 3) << 4);
      bF[n] = *(const f16x8*)(Bs + byte);
    }
#pragma unroll
    for (int m = 0; m < 4; m++)
#pragma unroll
      for (int n = 0; n < 4; n++)
        acc[m][n] = __builtin_amdgcn_mfma_f32_16x16x32_f16(aF[m], bF[n], acc[m][n], 0, 0, 0);
  }
  size_t base = (wv >= 2) ? (size_t)PC : 0;
  int col0 = (wv & 1) * 64;
#pragma unroll
  for (int m = 0; m < 4; m++)
#pragma unroll
    for (int n = 0; n < 4; n++) {
      int col = col0 + n * 16 + lo;
#pragma unroll
      for (int rr = 0; rr < 4; rr++) {
        int px = p0 + m * 16 + hi * 4 + rr;
        mOut[base + (size_t)px * 128 + col] = __float2half(sigf(acc[m][n][rr]));
      }
    }
}

// ---------------- fused 2-step scan: a1 = S u (own 4 taps), a2 = S^2 u (16 taps)
// MODE 0: acc = u_own + a1 + a2 (init), store a2.  MODE 1: acc += a1+a2, store a2.
// MODE 2 (final pair): out = sigmoid(acc + a1 + a2); no acc/state store.
template <int MODE>
__global__ __launch_bounds__(256) void fused_kernel(const __half* __restrict__ inb,
                                                    __half* __restrict__ outb,
                                                    __half* __restrict__ accb,
                                                    const uint4* __restrict__ c2g) {
  __shared__ uint4 c2s[160];                 // 16 slots x 160B
  int tid = threadIdx.x;
  if (tid < 160) c2s[tid] = c2g[(size_t)blockIdx.x * 160 + tid];
  __syncthreads();
  const Coef2 c = ((const Coef2*)c2s)[tid >> 4];
  int gtid = blockIdx.x * 256 + tid;
  int slot = gtid >> 4;                      // chain*32768 + pixel
  int ch = (gtid & 15) << 3;                 // 8 channels per thread
  int chain = slot >> 15;
  size_t cb = (size_t)chain * PC;
  const __half* pin = inb + cb;
  int rowel = ((slot & 32767) << 7) + ch;

  float r[8];
  {
    float t0[8], t1[8], t2[8], t3[8];
    h8f(*(const H8*)(pin + c.oa.x + ch), t0);
    h8f(*(const H8*)(pin + c.oa.y + ch), t1);
    h8f(*(const H8*)(pin + c.oa.z + ch), t2);
    h8f(*(const H8*)(pin + c.oa.w + ch), t3);
#pragma unroll
    for (int i = 0; i < 8; i++)
      r[i] = c.wa.x * t0[i] + c.wa.y * t1[i] + c.wa.z * t2[i] + c.wa.w * t3[i];
  }
  float a2[8] = {};
#define GRP(O, W) { \
    float t0[8], t1[8], t2[8], t3[8]; \
    h8f(*(const H8*)(pin + (O).x + ch), t0); \
    h8f(*(const H8*)(pin + (O).y + ch), t1); \
    h8f(*(const H8*)(pin + (O).z + ch), t2); \
    h8f(*(const H8*)(pin + (O).w + ch), t3); \
    _Pragma("unroll") \
    for (int i = 0; i < 8; i++) \
      a2[i] += (W).x * t0[i] + (W).y * t1[i] + (W).z * t2[i] + (W).w * t3[i]; }
  GRP(c.oc0, c.wc0)
  GRP(c.oc1, c.wc1)
  GRP(c.oc2, c.wc2)
  GRP(c.oc3, c.wc3)
#undef GRP
#pragma unroll
  for (int i = 0; i < 8; i++) r[i] += a2[i];  // r = a1 + a2

  if (MODE == 2) {
    float af[8];
    h8f(*(const H8*)(accb + cb + rowel), af);
#pragma unroll
    for (int i = 0; i < 8; i++) r[i] = sigf(af[i] + r[i]);
    *(H8*)(outb + cb + rowel) = f8h(r);
  } else {
    *(H8*)(outb + cb + rowel) = f8h(a2);     // new state = a2
    float af[8];
    if (MODE == 0) h8f(*(const H8*)(pin + rowel), af);          // acc = m + ...
    else           h8f(*(const H8*)(accb + cb + rowel), af);
#pragma unroll
    for (int i = 0; i < 8; i++) af[i] += r[i];
    *(H8*)(accb + cb + rowel) = f8h(af);
  }
}

// ---------------- depthwise 3x3, zero pad, fp16 in/out, f32 weights/accum
template <int C>
__global__ __launch_bounds__(256) void dw_kernel(const __half* __restrict__ in,
                                                 const float* __restrict__ wT,
                                                 __half* __restrict__ out) {
  int tid = threadIdx.x;
  constexpr int TPP = C / 8;
  constexpr int PPB = 256 / TPP;
  int slot = blockIdx.x * PPB + tid / TPP;
  int ch = (tid % TPP) * 8;
  int b = slot >> 14, h = (slot >> 7) & 127, w = slot & 127;
  const __half* src;
  int choff;
  if (C == 256) { src = in + ((ch < 128) ? 0 : (size_t)PC); choff = ch & 127; }
  else          { src = in; choff = ch; }
  float acc[8] = {};
#pragma unroll
  for (int t = 0; t < 9; t++) {
    int dy = t / 3 - 1, dx = t % 3 - 1;
    int yy = h + dy, xx = w + dx;
    if (yy < 0 || yy > 127 || xx < 0 || xx > 127) continue;
    int q = (b << 14) + yy * 128 + xx;
    float v[8];
    h8f(*(const H8*)(src + (size_t)q * 128 + choff), v);
    float4 wa = *(const float4*)(wT + t * C + ch);
    float4 wb = *(const float4*)(wT + t * C + ch + 4);
    acc[0] = fmaf(wa.x, v[0], acc[0]);
    acc[1] = fmaf(wa.y, v[1], acc[1]);
    acc[2] = fmaf(wa.z, v[2], acc[2]);
    acc[3] = fmaf(wa.w, v[3], acc[3]);
    acc[4] = fmaf(wb.x, v[4], acc[4]);
    acc[5] = fmaf(wb.y, v[5], acc[5]);
    acc[6] = fmaf(wb.z, v[6], acc[6]);
    acc[7] = fmaf(wb.w, v[7], acc[7]);
  }
  *(H8*)(out + (size_t)slot * C + ch) = f8h(acc);
}

// ---------------- pointwise 1x1 (fp16 channels-last in, f32 weights) + bias
template <int CIN, bool NCHW>
__global__ __launch_bounds__(256) void pw_kernel(const __half* __restrict__ in,
                                                 const float* __restrict__ w,
                                                 const float* __restrict__ bias,
                                                 void* __restrict__ outv) {
  __shared__ float xsT[32][132];
  __shared__ float wsT[32][40];
  int tid = threadIdx.x;
  int p0 = blockIdx.x * 128;
  int co0 = blockIdx.y * 32;
  int pxg = tid & 31, cog = tid >> 5;
  float acc[4][4] = {};
  for (int ci0 = 0; ci0 < CIN; ci0 += 32) {
#pragma unroll
    for (int pass = 0; pass < 2; pass++) {
      int idx = tid + pass * 256;
      int px = idx >> 2, c8 = (idx & 3) * 8;
      float f[8];
      h8f(*(const H8*)(in + (size_t)(p0 + px) * CIN + ci0 + c8), f);
#pragma unroll
      for (int i = 0; i < 8; i++) xsT[c8 + i][px] = f[i];
    }
    {
      int co = tid >> 3, c4 = (tid & 7) * 4;
      float4 v = *(const float4*)(w + (size_t)(co0 + co) * CIN + ci0 + c4);
      wsT[c4 + 0][co] = v.x; wsT[c4 + 1][co] = v.y; wsT[c4 + 2][co] = v.z; wsT[c4 + 3][co] = v.w;
    }
    __syncthreads();
#pragma unroll
    for (int ci = 0; ci < 32; ci++) {
      float4 xv = *(const float4*)&xsT[ci][pxg * 4];
      float4 wv = *(const float4*)&wsT[ci][cog * 4];
      float xa[4] = {xv.x, xv.y, xv.z, xv.w};
      float wa[4] = {wv.x, wv.y, wv.z, wv.w};
#pragma unroll
      for (int i = 0; i < 4; i++)
#pragma unroll
        for (int j = 0; j < 4; j++)
          acc[i][j] = fmaf(xa[i], wa[j], acc[i][j]);
    }
    __syncthreads();
  }
  float4 bv = *(const float4*)(bias + co0 + cog * 4);
  float ba[4] = {bv.x, bv.y, bv.z, bv.w};
  if (NCHW) {
    float* out = (float*)outv;
    int b = p0 >> 14, hw0 = p0 & 16383;
#pragma unroll
    for (int j = 0; j < 4; j++) {
      int co = co0 + cog * 4 + j;
#pragma unroll
      for (int i = 0; i < 4; i++)
        out[(size_t)(b * 128 + co) * HW + hw0 + pxg * 4 + i] = acc[i][j] + ba[j];
    }
  } else {
    __half* out = (__half*)outv;
#pragma unroll
    for (int i = 0; i < 4; i++) {
      H4 hv;
      hv.h[0] = __floats2half2_rn(acc[i][0] + ba[0], acc[i][1] + ba[1]);
      hv.h[1] = __floats2half2_rn(acc[i][2] + ba[2], acc[i][3] + ba[3]);
      *(H4*)(out + (size_t)(p0 + pxg * 4 + i) * 128 + co0 + cog * 4) = hv;
    }
  }
}

extern "C" void kernel_launch(void* const* d_in, const int* in_sizes, int n_in,
                              void* d_out, int out_size, void* d_ws, size_t ws_size,
                              hipStream_t stream) {
  const float* x     = (const float*)d_in[0];
  const float* grads = (const float*)d_in[1];
  const float* w1    = (const float*)d_in[2];
  const float* w2    = (const float*)d_in[3];
  const float* mdw   = (const float*)d_in[4];
  const float* mpw   = (const float*)d_in[5];
  const float* mb    = (const float*)d_in[6];
  const float* pdw   = (const float*)d_in[7];
  const float* ppw   = (const float*)d_in[8];
  const float* pb    = (const float*)d_in[9];
  float* out = (float*)d_out;
  char* wsb = (char*)d_ws;

  __half* BUF0 = (__half*)wsb;
  __half* BUF1 = (__half*)(wsb + (size_t)16777216);
  __half* ACC  = (__half*)(wsb + (size_t)33554432);
  Coef2* C2    = (Coef2*)(wsb + (size_t)50331648);           // 10,485,760 B
  __half* WT16 = (__half*)(wsb + (size_t)60817408);          // 131,072 B
  float* wdwT  = (float*)(wsb + (size_t)60948480);
  float* pdwT  = wdwT + 2304;

  coef2_kernel<<<256, 256, 0, stream>>>(grads, C2);
  tw_kernel<<<270, 256, 0, stream>>>(mdw, pdw, w1, w2, wdwT, pdwT, WT16);
  conv1_kernel<<<512, 256, 0, stream>>>(x, WT16, BUF0);

  const uint4* c2u = (const uint4*)C2;
  fused_kernel<0><<<4096, 256, 0, stream>>>(BUF0, BUF1, ACC, c2u);
  for (int k = 1; k < 11; k++) {
    const __half* in_ = (k & 1) ? BUF1 : BUF0;
    __half* out_      = (k & 1) ? BUF0 : BUF1;
    fused_kernel<1><<<4096, 256, 0, stream>>>(in_, out_, ACC, c2u);
  }
  fused_kernel<2><<<4096, 256, 0, stream>>>(BUF1, BUF0, ACC, c2u);

  // BUF0 = sigmoid(s1) chain A (+0), sigmoid(s2) chain B (+PC), fp16 channels-last
  __half* DW1 = BUF1;        // [P][256] fp16
  __half* PW1 = ACC;         // [P][128] fp16
  __half* DW2 = ACC + PC;    // [P][128] fp16
  dw_kernel<256><<<4096, 256, 0, stream>>>(BUF0, wdwT, DW1);
  pw_kernel<256, false><<<dim3(256, 4), 256, 0, stream>>>(DW1, mpw, mb, (void*)PW1);
  dw_kernel<128><<<2048, 256, 0, stream>>>(PW1, pdwT, DW2);
  pw_kernel<128, true ><<<dim3(256, 4), 256, 0, stream>>>(DW2, ppw, pb, (void*)out);
}

// Round 5
// 293.087 us; speedup vs baseline: 2.5444x; 1.1363x over previous
//
#include <hip/hip_runtime.h>
#include <hip/hip_fp16.h>

// FlowLayer: B=2, CIN=256, COUT=128, H=W=128, iters=24.
// s = sum_{k=0..24} S^k m  =  m + (S+S^2) t,   t = (I+S^2)(I+S^4)(I+S^8+S^16) m
// -> 11 applications of the 16-tap composed S^2 stencil + 1 final 20-tap kernel,
//    only 5 launches touch an accumulator (own-pixel adds), no per-step acc RMW.
// P = 32768 pixels; PC = P*128 elements per chain buffer (fp16, 8.4 MB; x2 chains = 16.8 MB).
// ws (bytes): M@0, A@16M, B@32M, Pb@48M, Qb@64M (16.8MB each, 2-chain)
//             C2tab@80M (65536x128B), C1tab@+8.4M (65536x32B), WT16, WPW1, WPW2, wdwT, pdwT

#define PC 4194304
#define HW 16384

struct CoefC { int4 o0; float4 w0; int4 o1; float4 w1; int4 o2; float4 w2; int4 o3; float4 w3; };
struct Coef1 { int4 oa; float4 wa; };

struct alignas(16) H8 { __half2 h[4]; };
struct alignas(8)  H4 { __half2 h[2]; };
typedef _Float16 f16x8 __attribute__((ext_vector_type(8)));
typedef float f32x4 __attribute__((ext_vector_type(4)));

__device__ __forceinline__ float sigf(float v) { return 1.0f / (1.0f + __expf(-v)); }

__device__ __forceinline__ void h8f(const H8& v, float* f) {
#pragma unroll
  for (int i = 0; i < 4; i++) { float2 t = __half22float2(v.h[i]); f[2*i] = t.x; f[2*i+1] = t.y; }
}
__device__ __forceinline__ H8 f8h(const float* f) {
  H8 r;
#pragma unroll
  for (int i = 0; i < 4; i++) r.h[i] = __floats2half2_rn(f[2*i], f[2*i+1]);
  return r;
}

// ---------------- per-pixel bilinear stencil
__device__ __forceinline__ void stencil(const float* __restrict__ g, float sgn, int pix,
                                        int4& op, float4& wt) {
  int b = pix >> 14, hw = pix & 16383;
  int h = hw >> 7, w = hw & 127;
  float gx = g[(size_t)(b * 2 + 0) * HW + hw];
  float gy = g[(size_t)(b * 2 + 1) * HW + hw];
  float xp = (float)w + sgn * gx;
  float yp = (float)h + sgn * gy;
  float x0f = floorf(xp), y0f = floorf(yp);
  float fx = xp - x0f, fy = yp - y0f;
  int x0 = (int)x0f, y0 = (int)y0f;
  int x1 = x0 + 1, y1 = y0 + 1;
  bool vx0 = (x0 >= 0) && (x0 <= 127);
  bool vx1 = (x1 >= 0) && (x1 <= 127);
  bool vy0 = (y0 >= 0) && (y0 <= 127);
  bool vy1 = (y1 >= 0) && (y1 <= 127);
  int x0c = min(max(x0, 0), 127), x1c = min(max(x1, 0), 127);
  int y0c = min(max(y0, 0), 127), y1c = min(max(y1, 0), 127);
  int bb = b << 14;
  op.x = bb + y0c * 128 + x0c;
  op.y = bb + y0c * 128 + x1c;
  op.z = bb + y1c * 128 + x0c;
  op.w = bb + y1c * 128 + x1c;
  wt.x = (vx0 && vy0) ? (1.f - fx) * (1.f - fy) : 0.f;
  wt.y = (vx1 && vy0) ? fx * (1.f - fy) : 0.f;
  wt.z = (vx0 && vy1) ? (1.f - fx) * fy : 0.f;
  wt.w = (vx1 && vy1) ? fx * fy : 0.f;
}

__device__ __forceinline__ int4 shl7(int4 v) {
  return make_int4(v.x << 7, v.y << 7, v.z << 7, v.w << 7);
}
__device__ __forceinline__ float4 scale4(float4 v, float s) {
  return make_float4(v.x * s, v.y * s, v.z * s, v.w * s);
}

// ---------------- stencil tables: C1 = single-S (4 taps), C2 = composed S^2 (16 taps)
__global__ __launch_bounds__(256) void coef2_kernel(const float* __restrict__ grads,
                                                    Coef1* __restrict__ c1,
                                                    CoefC* __restrict__ c2) {
  int idx = blockIdx.x * 256 + threadIdx.x;   // 0..65535
  int chain = idx >> 15;
  int p = idx & 32767;
  float sgn = chain ? -3.96875f : 3.96875f;   // 63.5*1.5/24
  int4 op; float4 ow;
  stencil(grads, sgn, p, op, ow);
  Coef1 a; a.oa = shl7(op); a.wa = ow;
  c1[idx] = a;
  CoefC c;
  int4 o2; float4 nw;
  stencil(grads, sgn, op.x, o2, nw); c.o0 = shl7(o2); c.w0 = scale4(nw, ow.x);
  stencil(grads, sgn, op.y, o2, nw); c.o1 = shl7(o2); c.w1 = scale4(nw, ow.y);
  stencil(grads, sgn, op.z, o2, nw); c.o2 = shl7(o2); c.w2 = scale4(nw, ow.z);
  stencil(grads, sgn, op.w, o2, nw); c.o3 = shl7(o2); c.w3 = scale4(nw, ow.w);
  c2[idx] = c;
}

// ---------------- weight prep
__global__ __launch_bounds__(256) void tw_kernel(const float* __restrict__ mdw,
                                                 const float* __restrict__ pdw,
                                                 const float* __restrict__ w1,
                                                 const float* __restrict__ w2,
                                                 const float* __restrict__ mpw,
                                                 const float* __restrict__ ppw,
                                                 float* __restrict__ wdwT,
                                                 float* __restrict__ pdwT,
                                                 __half* __restrict__ wT16,
                                                 __half* __restrict__ wpw1,
                                                 __half* __restrict__ wpw2) {
  int i = blockIdx.x * 256 + threadIdx.x;
  if (i < 65536) {
    int co = i >> 8, ci = i & 255;
    float v = (co < 128) ? w1[co * 256 + ci] : w2[(size_t)(co - 128) * 256 + ci];
    wT16[i] = __float2half(v);
  } else if (i < 98304) {
    int j = i - 65536;                 // [128co][256ci]
    wpw1[j] = __float2half(mpw[j]);
  } else if (i < 114688) {
    int j = i - 98304;                 // [128co][128ci]
    wpw2[j] = __float2half(ppw[j]);
  } else if (i < 116992) {
    int j = i - 114688;
    int ch = j / 9, t = j % 9;
    wdwT[t * 256 + ch] = mdw[j];
  } else if (i < 118144) {
    int j = i - 116992;
    int ch = j / 9, t = j % 9;
    pdwT[t * 128 + ch] = pdw[j];
  }
}

// ---------------- conv1x1 via f16 MFMA (unchanged from round 4; verified)
__global__ __launch_bounds__(256) void conv1_kernel(const float* __restrict__ x,
                                                    const __half* __restrict__ wT16,
                                                    __half* __restrict__ mOut) {
  __shared__ __align__(16) char As[4096];
  __shared__ __align__(16) char Bs[16384];
  int tid = threadIdx.x;
  int p0 = blockIdx.x * 64;
  int b = p0 >> 14;
  int hw0 = p0 & 16383;
  int wv = tid >> 6, ln = tid & 63;
  int hi = ln >> 4, lo = ln & 15;
  f32x4 acc[4][4] = {};
  const float* xb = x + (size_t)b * 256 * HW + hw0;
  int apx = tid & 63, ac8 = (tid >> 6) * 8;
  int abyte = (apx * 64 + ac8 * 2) ^ ((apx & 3) << 4);
  for (int k = 0; k < 256; k += 32) {
    f16x8 av;
#pragma unroll
    for (int j = 0; j < 8; j++) av[j] = (_Float16)xb[(size_t)(k + ac8 + j) * HW + apx];
    if (k) __syncthreads();
    *(f16x8*)(As + abyte) = av;
    {
      const __half* src = wT16 + (size_t)tid * 256 + k;
#pragma unroll
      for (int s = 0; s < 4; s++) {
        f16x8 bv = *(const f16x8*)(src + s * 8);
        int byte = (tid * 64 + s * 16) ^ ((tid & 3) << 4);
        *(f16x8*)(Bs + byte) = bv;
      }
    }
    __syncthreads();
    f16x8 aF[4], bF[4];
#pragma unroll
    for (int m = 0; m < 4; m++) {
      int px = m * 16 + lo;
      int byte = (px * 64 + hi * 16) ^ ((px & 3) << 4);
      aF[m] = *(const f16x8*)(As + byte);
    }
#pragma unroll
    for (int n = 0; n < 4; n++) {
      int co = wv * 64 + n * 16 + lo;
      int byte = (co * 64 + hi * 16) ^ ((co & 3) << 4);
      bF[n] = *(const f16x8*)(Bs + byte);
    }
#pragma unroll
    for (int m = 0; m < 4; m++)
#pragma unroll
      for (int n = 0; n < 4; n++)
        acc[m][n] = __builtin_amdgcn_mfma_f32_16x16x32_f16(aF[m], bF[n], acc[m][n], 0, 0, 0);
  }
  size_t base = (wv >= 2) ? (size_t)PC : 0;
  int col0 = (wv & 1) * 64;
#pragma unroll
  for (int m = 0; m < 4; m++)
#pragma unroll
    for (int n = 0; n < 4; n++) {
      int col = col0 + n * 16 + lo;
#pragma unroll
      for (int rr = 0; rr < 4; rr++) {
        int px = p0 + m * 16 + hi * 4 + rr;
        mOut[base + (size_t)px * 128 + col] = __float2half(sigf(acc[m][n][rr]));
      }
    }
}

// ---------------- S^2 application (16 taps). ACC 0: none; 1: accOut = accAdd_own + res;
// 2: accOut += res.  State write always: outb = res.
template <int ACC>
__global__ __launch_bounds__(256) void s2_kernel(const __half* __restrict__ inb,
                                                 __half* __restrict__ outb,
                                                 const __half* __restrict__ accAdd,
                                                 __half* __restrict__ accOut,
                                                 const uint4* __restrict__ c2tab) {
  __shared__ uint4 cs[128];                  // 16 slots x 128B
  int tid = threadIdx.x;
  if (tid < 128) cs[tid] = c2tab[(size_t)blockIdx.x * 128 + tid];
  __syncthreads();
  const CoefC c = ((const CoefC*)cs)[tid >> 4];
  int gtid = blockIdx.x * 256 + tid;
  int slot = gtid >> 4;
  int ch = (gtid & 15) << 3;
  int chain = slot >> 15;
  size_t cb = (size_t)chain * PC;
  const __half* pin = inb + cb;
  int rowel = ((slot & 32767) << 7) + ch;

  float a2[8] = {};
#define GRP(O, W) { \
    float t0[8], t1[8], t2[8], t3[8]; \
    h8f(*(const H8*)(pin + (O).x + ch), t0); \
    h8f(*(const H8*)(pin + (O).y + ch), t1); \
    h8f(*(const H8*)(pin + (O).z + ch), t2); \
    h8f(*(const H8*)(pin + (O).w + ch), t3); \
    _Pragma("unroll") \
    for (int i = 0; i < 8; i++) \
      a2[i] += (W).x * t0[i] + (W).y * t1[i] + (W).z * t2[i] + (W).w * t3[i]; }
  GRP(c.o0, c.w0)
  GRP(c.o1, c.w1)
  GRP(c.o2, c.w2)
  GRP(c.o3, c.w3)
#undef GRP
  *(H8*)(outb + cb + rowel) = f8h(a2);
  if (ACC == 1) {
    float af[8];
    h8f(*(const H8*)(accAdd + cb + rowel), af);
#pragma unroll
    for (int i = 0; i < 8; i++) af[i] += a2[i];
    *(H8*)(accOut + cb + rowel) = f8h(af);
  } else if (ACC == 2) {
    float af[8];
    h8f(*(const H8*)(accOut + cb + rowel), af);
#pragma unroll
    for (int i = 0; i < 8; i++) af[i] += a2[i];
    *(H8*)(accOut + cb + rowel) = f8h(af);
  }
}

// ---------------- final: out = sigmoid(m_own + S t + S^2 t)  (4 + 16 taps from t)
__global__ __launch_bounds__(256) void fin_kernel(const __half* __restrict__ tb,
                                                  const __half* __restrict__ mb,
                                                  const uint4* __restrict__ c1tab,
                                                  const uint4* __restrict__ c2tab,
                                                  __half* __restrict__ outb) {
  __shared__ uint4 c2s[128];
  __shared__ uint4 c1s[32];
  int tid = threadIdx.x;
  if (tid < 128) c2s[tid] = c2tab[(size_t)blockIdx.x * 128 + tid];
  if (tid < 32)  c1s[tid] = c1tab[(size_t)blockIdx.x * 32 + tid];
  __syncthreads();
  const CoefC c = ((const CoefC*)c2s)[tid >> 4];
  const Coef1 a = ((const Coef1*)c1s)[tid >> 4];
  int gtid = blockIdx.x * 256 + tid;
  int slot = gtid >> 4;
  int ch = (gtid & 15) << 3;
  int chain = slot >> 15;
  size_t cb = (size_t)chain * PC;
  const __half* pin = tb + cb;
  int rowel = ((slot & 32767) << 7) + ch;

  float r[8] = {};
#define GRP(O, W) { \
    float t0[8], t1[8], t2[8], t3[8]; \
    h8f(*(const H8*)(pin + (O).x + ch), t0); \
    h8f(*(const H8*)(pin + (O).y + ch), t1); \
    h8f(*(const H8*)(pin + (O).z + ch), t2); \
    h8f(*(const H8*)(pin + (O).w + ch), t3); \
    _Pragma("unroll") \
    for (int i = 0; i < 8; i++) \
      r[i] += (W).x * t0[i] + (W).y * t1[i] + (W).z * t2[i] + (W).w * t3[i]; }
  GRP(a.oa, a.wa)
  GRP(c.o0, c.w0)
  GRP(c.o1, c.w1)
  GRP(c.o2, c.w2)
  GRP(c.o3, c.w3)
#undef GRP
  float mf[8];
  h8f(*(const H8*)(mb + cb + rowel), mf);
#pragma unroll
  for (int i = 0; i < 8; i++) r[i] = sigf(mf[i] + r[i]);
  *(H8*)(outb + cb + rowel) = f8h(r);
}

// ---------------- depthwise 3x3, zero pad, fp16 in/out, f32 weights/accum
template <int C>
__global__ __launch_bounds__(256) void dw_kernel(const __half* __restrict__ in,
                                                 const float* __restrict__ wT,
                                                 __half* __restrict__ out) {
  int tid = threadIdx.x;
  constexpr int TPP = C / 8;
  constexpr int PPB = 256 / TPP;
  int slot = blockIdx.x * PPB + tid / TPP;
  int ch = (tid % TPP) * 8;
  int b = slot >> 14, h = (slot >> 7) & 127, w = slot & 127;
  const __half* src;
  int choff;
  if (C == 256) { src = in + ((ch < 128) ? 0 : (size_t)PC); choff = ch & 127; }
  else          { src = in; choff = ch; }
  float acc[8] = {};
#pragma unroll
  for (int t = 0; t < 9; t++) {
    int dy = t / 3 - 1, dx = t % 3 - 1;
    int yy = h + dy, xx = w + dx;
    if (yy < 0 || yy > 127 || xx < 0 || xx > 127) continue;
    int q = (b << 14) + yy * 128 + xx;
    float v[8];
    h8f(*(const H8*)(src + (size_t)q * 128 + choff), v);
    float4 wa = *(const float4*)(wT + t * C + ch);
    float4 wb = *(const float4*)(wT + t * C + ch + 4);
    acc[0] = fmaf(wa.x, v[0], acc[0]);
    acc[1] = fmaf(wa.y, v[1], acc[1]);
    acc[2] = fmaf(wa.z, v[2], acc[2]);
    acc[3] = fmaf(wa.w, v[3], acc[3]);
    acc[4] = fmaf(wb.x, v[4], acc[4]);
    acc[5] = fmaf(wb.y, v[5], acc[5]);
    acc[6] = fmaf(wb.z, v[6], acc[6]);
    acc[7] = fmaf(wb.w, v[7], acc[7]);
  }
  *(H8*)(out + (size_t)slot * C + ch) = f8h(acc);
}

// ---------------- pw1: [P]x[256] @ w[128co][256ci] -> fp16 channels-last [P][128]
// A = weights (M=128 co), B = pixels (N=64 px/block, 16 per wave) -> contiguous f16 stores.
__global__ __launch_bounds__(256) void pw1_kernel(const __half* __restrict__ in,
                                                  const __half* __restrict__ w16,
                                                  const float* __restrict__ bias,
                                                  __half* __restrict__ out) {
  int tid = threadIdx.x;
  int p0 = blockIdx.x * 64;
  int wv = tid >> 6, ln = tid & 63;
  int hi = ln >> 4, lo = ln & 15;
  int px = p0 + wv * 16 + lo;
  f32x4 acc[8] = {};
  for (int k = 0; k < 256; k += 32) {
    f16x8 bF = *(const f16x8*)(in + (size_t)px * 256 + k + hi * 8);
#pragma unroll
    for (int m = 0; m < 8; m++) {
      f16x8 aF = *(const f16x8*)(w16 + (size_t)(m * 16 + lo) * 256 + k + hi * 8);
      acc[m] = __builtin_amdgcn_mfma_f32_16x16x32_f16(aF, bF, acc[m], 0, 0, 0);
    }
  }
  // D: col(lane&15)=px-lane, row=(lane>>4)*4+reg = co
  int opx = p0 + wv * 16 + lo;
#pragma unroll
  for (int m = 0; m < 8; m++) {
    int co = m * 16 + hi * 4;
    float4 bv = *(const float4*)(bias + co);
    H4 hv;
    hv.h[0] = __floats2half2_rn(acc[m][0] + bv.x, acc[m][1] + bv.y);
    hv.h[1] = __floats2half2_rn(acc[m][2] + bv.z, acc[m][3] + bv.w);
    *(H4*)(out + (size_t)opx * 128 + co) = hv;
  }
}

// ---------------- pw2: [P]x[128] @ w[128co][128ci] -> f32 NCHW output + bias
__global__ __launch_bounds__(256) void pw2_kernel(const __half* __restrict__ in,
                                                  const __half* __restrict__ w16,
                                                  const float* __restrict__ bias,
                                                  float* __restrict__ out) {
  int tid = threadIdx.x;
  int p0 = blockIdx.x * 64;
  int b = p0 >> 14;
  int hw0 = p0 & 16383;
  int wv = tid >> 6, ln = tid & 63;
  int hi = ln >> 4, lo = ln & 15;
  int co0 = wv * 32;
  f32x4 acc[4][2] = {};
  for (int k = 0; k < 128; k += 32) {
    f16x8 aF[4], bF[2];
#pragma unroll
    for (int m = 0; m < 4; m++)
      aF[m] = *(const f16x8*)(in + (size_t)(p0 + m * 16 + lo) * 128 + k + hi * 8);
#pragma unroll
    for (int n = 0; n < 2; n++)
      bF[n] = *(const f16x8*)(w16 + (size_t)(co0 + n * 16 + lo) * 128 + k + hi * 8);
#pragma unroll
    for (int m = 0; m < 4; m++)
#pragma unroll
      for (int n = 0; n < 2; n++)
        acc[m][n] = __builtin_amdgcn_mfma_f32_16x16x32_f16(aF[m], bF[n], acc[m][n], 0, 0, 0);
  }
#pragma unroll
  for (int m = 0; m < 4; m++)
#pragma unroll
    for (int n = 0; n < 2; n++) {
      int co = co0 + n * 16 + lo;
      float bb = bias[co];
      float4 v = {acc[m][n][0] + bb, acc[m][n][1] + bb, acc[m][n][2] + bb, acc[m][n][3] + bb};
      *(float4*)(out + (size_t)(b * 128 + co) * HW + hw0 + m * 16 + hi * 4) = v;
    }
}

extern "C" void kernel_launch(void* const* d_in, const int* in_sizes, int n_in,
                              void* d_out, int out_size, void* d_ws, size_t ws_size,
                              hipStream_t stream) {
  const float* x     = (const float*)d_in[0];
  const float* grads = (const float*)d_in[1];
  const float* w1    = (const float*)d_in[2];
  const float* w2    = (const float*)d_in[3];
  const float* mdw   = (const float*)d_in[4];
  const float* mpw   = (const float*)d_in[5];
  const float* mb    = (const float*)d_in[6];
  const float* pdw   = (const float*)d_in[7];
  const float* ppw   = (const float*)d_in[8];
  const float* pb    = (const float*)d_in[9];
  float* out = (float*)d_out;
  char* wsb = (char*)d_ws;

  __half* M  = (__half*)wsb;
  __half* A  = (__half*)(wsb + (size_t)16777216);
  __half* Bb = (__half*)(wsb + (size_t)33554432);
  __half* Pb = (__half*)(wsb + (size_t)50331648);
  __half* Qb = (__half*)(wsb + (size_t)67108864);
  CoefC* C2  = (CoefC*)(wsb + (size_t)83886080);      // 8,388,608 B
  Coef1* C1  = (Coef1*)(wsb + (size_t)92274688);      // 2,097,152 B
  __half* WT16 = (__half*)(wsb + (size_t)94371840);   // 131,072
  __half* WPW1 = (__half*)(wsb + (size_t)94502912);   // 65,536
  __half* WPW2 = (__half*)(wsb + (size_t)94568448);   // 32,768
  float* wdwT  = (float*)(wsb + (size_t)94601216);
  float* pdwT  = wdwT + 2304;

  const uint4* c2u = (const uint4*)C2;
  const uint4* c1u = (const uint4*)C1;

  coef2_kernel<<<256, 256, 0, stream>>>(grads, C1, C2);
  tw_kernel<<<462, 256, 0, stream>>>(mdw, pdw, w1, w2, mpw, ppw, wdwT, pdwT, WT16, WPW1, WPW2);
  conv1_kernel<<<512, 256, 0, stream>>>(x, WT16, M);

  // u-chain: p = (I + S^8 + S^16) m   (P buffer)
  s2_kernel<0><<<4096, 256, 0, stream>>>(M,  A,  nullptr, nullptr, c2u);   // S^2 m
  s2_kernel<0><<<4096, 256, 0, stream>>>(A,  Bb, nullptr, nullptr, c2u);   // S^4
  s2_kernel<0><<<4096, 256, 0, stream>>>(Bb, A,  nullptr, nullptr, c2u);   // S^6
  s2_kernel<1><<<4096, 256, 0, stream>>>(A,  Bb, M,       Pb,      c2u);   // S^8 ; P=m+S^8m
  s2_kernel<0><<<4096, 256, 0, stream>>>(Bb, A,  nullptr, nullptr, c2u);   // S^10
  s2_kernel<0><<<4096, 256, 0, stream>>>(A,  Bb, nullptr, nullptr, c2u);   // S^12
  s2_kernel<0><<<4096, 256, 0, stream>>>(Bb, A,  nullptr, nullptr, c2u);   // S^14
  s2_kernel<2><<<4096, 256, 0, stream>>>(A,  Bb, nullptr, Pb,      c2u);   // S^16 ; P+=S^16m
  // q = (I + S^4) p   (Q buffer);  t = (I + S^2) q  (reuse P)
  s2_kernel<0><<<4096, 256, 0, stream>>>(Pb, A,  nullptr, nullptr, c2u);   // S^2 p
  s2_kernel<1><<<4096, 256, 0, stream>>>(A,  Bb, Pb,      Qb,      c2u);   // S^4 p ; Q=p+S^4p
  s2_kernel<1><<<4096, 256, 0, stream>>>(Qb, A,  Qb,      Pb,      c2u);   // S^2 q ; T(P)=q+S^2q
  // s = sigmoid(m + (S + S^2) t) -> A (both chains)
  fin_kernel<<<4096, 256, 0, stream>>>(Pb, M, c1u, c2u, A);

  // merge stage
  __half* DW1 = Bb;          // [P][256] fp16
  __half* PW1 = Qb;          // [P][128] fp16
  __half* DW2 = Qb + PC;     // [P][128] fp16
  dw_kernel<256><<<4096, 256, 0, stream>>>(A, wdwT, DW1);
  pw1_kernel<<<512, 256, 0, stream>>>(DW1, WPW1, mb, PW1);
  dw_kernel<128><<<2048, 256, 0, stream>>>(PW1, pdwT, DW2);
  pw2_kernel<<<512, 256, 0, stream>>>(DW2, WPW2, pb, out);
}

// Round 6
// 283.623 us; speedup vs baseline: 2.6293x; 1.0334x over previous
//
#include <hip/hip_runtime.h>
#include <hip/hip_fp16.h>

// FlowLayer: B=2, CIN=256, COUT=128, H=W=128, iters=24.
// s = sum_{k=0..24} S^k m  =  m + (S+S^2) t,   t = (I+S^2)(I+S^4)(I+S^8+S^16) m
// 11 x S^2 (16-tap) + 1 final 20-tap kernel. All scan/dw kernels use an
// XCD-aware block->slot mapping (bid&7 selects XCD; each XCD owns a contiguous
// half-image) so the ~16x tap reuse is served by the LOCAL 4MB L2 slice, and
// producer->consumer locality holds across launches (identical mapping).

#define PC 4194304
#define HW 16384

struct CoefC { int4 o0; float4 w0; int4 o1; float4 w1; int4 o2; float4 w2; int4 o3; float4 w3; };
struct Coef1 { int4 oa; float4 wa; };

struct alignas(16) H8 { __half2 h[4]; };
struct alignas(8)  H4 { __half2 h[2]; };
typedef _Float16 f16x8 __attribute__((ext_vector_type(8)));
typedef float f32x4 __attribute__((ext_vector_type(4)));

__device__ __forceinline__ float sigf(float v) { return 1.0f / (1.0f + __expf(-v)); }

__device__ __forceinline__ void h8f(const H8& v, float* f) {
#pragma unroll
  for (int i = 0; i < 4; i++) { float2 t = __half22float2(v.h[i]); f[2*i] = t.x; f[2*i+1] = t.y; }
}
__device__ __forceinline__ H8 f8h(const float* f) {
  H8 r;
#pragma unroll
  for (int i = 0; i < 4; i++) r.h[i] = __floats2half2_rn(f[2*i], f[2*i+1]);
  return r;
}

// XCD-aware slot base for 65536-slot space (2 chains x 2 batches = 4 images of 16384).
// image i -> XCD pair {2i,2i+1}; each XCD owns a half-image (2MB fp16, fits 4MB L2).
template <int SPB>
__device__ __forceinline__ int slot_base_64k(int bid) {
  int xcd = bid & 7;
  int i = xcd >> 1;          // image 0..3 (chain = i>>1, b = i&1)
  int half = xcd & 1;
  int sub = bid >> 3;        // 0 .. 8192/SPB-1
  return (i >> 1) * 32768 + (i & 1) * 16384 + half * 8192 + sub * SPB;
}
// 32768-slot space (2 batches): image b -> 4 XCDs, each a quarter-image.
template <int SPB>
__device__ __forceinline__ int slot_base_32k(int bid) {
  int xcd = bid & 7;
  int b = xcd >> 2;
  int q = xcd & 3;
  int sub = bid >> 3;        // 0 .. 4096/SPB-1
  return b * 16384 + q * 4096 + sub * SPB;
}

// ---------------- per-pixel bilinear stencil
__device__ __forceinline__ void stencil(const float* __restrict__ g, float sgn, int pix,
                                        int4& op, float4& wt) {
  int b = pix >> 14, hw = pix & 16383;
  int h = hw >> 7, w = hw & 127;
  float gx = g[(size_t)(b * 2 + 0) * HW + hw];
  float gy = g[(size_t)(b * 2 + 1) * HW + hw];
  float xp = (float)w + sgn * gx;
  float yp = (float)h + sgn * gy;
  float x0f = floorf(xp), y0f = floorf(yp);
  float fx = xp - x0f, fy = yp - y0f;
  int x0 = (int)x0f, y0 = (int)y0f;
  int x1 = x0 + 1, y1 = y0 + 1;
  bool vx0 = (x0 >= 0) && (x0 <= 127);
  bool vx1 = (x1 >= 0) && (x1 <= 127);
  bool vy0 = (y0 >= 0) && (y0 <= 127);
  bool vy1 = (y1 >= 0) && (y1 <= 127);
  int x0c = min(max(x0, 0), 127), x1c = min(max(x1, 0), 127);
  int y0c = min(max(y0, 0), 127), y1c = min(max(y1, 0), 127);
  int bb = b << 14;
  op.x = bb + y0c * 128 + x0c;
  op.y = bb + y0c * 128 + x1c;
  op.z = bb + y1c * 128 + x0c;
  op.w = bb + y1c * 128 + x1c;
  wt.x = (vx0 && vy0) ? (1.f - fx) * (1.f - fy) : 0.f;
  wt.y = (vx1 && vy0) ? fx * (1.f - fy) : 0.f;
  wt.z = (vx0 && vy1) ? (1.f - fx) * fy : 0.f;
  wt.w = (vx1 && vy1) ? fx * fy : 0.f;
}

__device__ __forceinline__ int4 shl7(int4 v) {
  return make_int4(v.x << 7, v.y << 7, v.z << 7, v.w << 7);
}
__device__ __forceinline__ float4 scale4(float4 v, float s) {
  return make_float4(v.x * s, v.y * s, v.z * s, v.w * s);
}

// ---------------- stencil tables
__global__ __launch_bounds__(256) void coef2_kernel(const float* __restrict__ grads,
                                                    Coef1* __restrict__ c1,
                                                    CoefC* __restrict__ c2) {
  int idx = blockIdx.x * 256 + threadIdx.x;
  int chain = idx >> 15;
  int p = idx & 32767;
  float sgn = chain ? -3.96875f : 3.96875f;   // 63.5*1.5/24
  int4 op; float4 ow;
  stencil(grads, sgn, p, op, ow);
  Coef1 a; a.oa = shl7(op); a.wa = ow;
  c1[idx] = a;
  CoefC c;
  int4 o2; float4 nw;
  stencil(grads, sgn, op.x, o2, nw); c.o0 = shl7(o2); c.w0 = scale4(nw, ow.x);
  stencil(grads, sgn, op.y, o2, nw); c.o1 = shl7(o2); c.w1 = scale4(nw, ow.y);
  stencil(grads, sgn, op.z, o2, nw); c.o2 = shl7(o2); c.w2 = scale4(nw, ow.z);
  stencil(grads, sgn, op.w, o2, nw); c.o3 = shl7(o2); c.w3 = scale4(nw, ow.w);
  c2[idx] = c;
}

// ---------------- weight prep
__global__ __launch_bounds__(256) void tw_kernel(const float* __restrict__ mdw,
                                                 const float* __restrict__ pdw,
                                                 const float* __restrict__ w1,
                                                 const float* __restrict__ w2,
                                                 const float* __restrict__ mpw,
                                                 const float* __restrict__ ppw,
                                                 float* __restrict__ wdwT,
                                                 float* __restrict__ pdwT,
                                                 __half* __restrict__ wT16,
                                                 __half* __restrict__ wpw1,
                                                 __half* __restrict__ wpw2) {
  int i = blockIdx.x * 256 + threadIdx.x;
  if (i < 65536) {
    int co = i >> 8, ci = i & 255;
    float v = (co < 128) ? w1[co * 256 + ci] : w2[(size_t)(co - 128) * 256 + ci];
    wT16[i] = __float2half(v);
  } else if (i < 98304) {
    int j = i - 65536;
    wpw1[j] = __float2half(mpw[j]);
  } else if (i < 114688) {
    int j = i - 98304;
    wpw2[j] = __float2half(ppw[j]);
  } else if (i < 116992) {
    int j = i - 114688;
    int ch = j / 9, t = j % 9;
    wdwT[t * 256 + ch] = mdw[j];
  } else if (i < 118144) {
    int j = i - 116992;
    int ch = j / 9, t = j % 9;
    pdwT[t * 128 + ch] = pdw[j];
  }
}

// ---------------- conv1x1 via f16 MFMA
__global__ __launch_bounds__(256) void conv1_kernel(const float* __restrict__ x,
                                                    const __half* __restrict__ wT16,
                                                    __half* __restrict__ mOut) {
  __shared__ __align__(16) char As[4096];
  __shared__ __align__(16) char Bs[16384];
  int tid = threadIdx.x;
  int p0 = blockIdx.x * 64;
  int b = p0 >> 14;
  int hw0 = p0 & 16383;
  int wv = tid >> 6, ln = tid & 63;
  int hi = ln >> 4, lo = ln & 15;
  f32x4 acc[4][4] = {};
  const float* xb = x + (size_t)b * 256 * HW + hw0;
  int apx = tid & 63, ac8 = (tid >> 6) * 8;
  int abyte = (apx * 64 + ac8 * 2) ^ ((apx & 3) << 4);
  for (int k = 0; k < 256; k += 32) {
    f16x8 av;
#pragma unroll
    for (int j = 0; j < 8; j++) av[j] = (_Float16)xb[(size_t)(k + ac8 + j) * HW + apx];
    if (k) __syncthreads();
    *(f16x8*)(As + abyte) = av;
    {
      const __half* src = wT16 + (size_t)tid * 256 + k;
#pragma unroll
      for (int s = 0; s < 4; s++) {
        f16x8 bv = *(const f16x8*)(src + s * 8);
        int byte = (tid * 64 + s * 16) ^ ((tid & 3) << 4);
        *(f16x8*)(Bs + byte) = bv;
      }
    }
    __syncthreads();
    f16x8 aF[4], bF[4];
#pragma unroll
    for (int m = 0; m < 4; m++) {
      int px = m * 16 + lo;
      int byte = (px * 64 + hi * 16) ^ ((px & 3) << 4);
      aF[m] = *(const f16x8*)(As + byte);
    }
#pragma unroll
    for (int n = 0; n < 4; n++) {
      int co = wv * 64 + n * 16 + lo;
      int byte = (co * 64 + hi * 16) ^ ((co & 3) << 4);
      bF[n] = *(const f16x8*)(Bs + byte);
    }
#pragma unroll
    for (int m = 0; m < 4; m++)
#pragma unroll
      for (int n = 0; n < 4; n++)
        acc[m][n] = __builtin_amdgcn_mfma_f32_16x16x32_f16(aF[m], bF[n], acc[m][n], 0, 0, 0);
  }
  size_t base = (wv >= 2) ? (size_t)PC : 0;
  int col0 = (wv & 1) * 64;
#pragma unroll
  for (int m = 0; m < 4; m++)
#pragma unroll
    for (int n = 0; n < 4; n++) {
      int col = col0 + n * 16 + lo;
#pragma unroll
      for (int rr = 0; rr < 4; rr++) {
        int px = p0 + m * 16 + hi * 4 + rr;
        mOut[base + (size_t)px * 128 + col] = __float2half(sigf(acc[m][n][rr]));
      }
    }
}

// ---------------- S^2 (16 taps), XCD-local mapping. ACC 0: none; 1: accOut=accAdd+res; 2: accOut+=res
template <int ACC>
__global__ __launch_bounds__(256) void s2_kernel(const __half* __restrict__ inb,
                                                 __half* __restrict__ outb,
                                                 const __half* __restrict__ accAdd,
                                                 __half* __restrict__ accOut,
                                                 const uint4* __restrict__ c2tab) {
  __shared__ uint4 cs[128];
  int tid = threadIdx.x;
  int slot0 = slot_base_64k<16>(blockIdx.x);
  if (tid < 128) cs[tid] = c2tab[(size_t)slot0 * 8 + tid];
  __syncthreads();
  const CoefC c = ((const CoefC*)cs)[tid >> 4];
  int slot = slot0 + (tid >> 4);
  int ch = (tid & 15) << 3;
  int chain = slot >> 15;
  size_t cb = (size_t)chain * PC;
  const __half* pin = inb + cb;
  int rowel = ((slot & 32767) << 7) + ch;

  float a2[8] = {};
#define GRP(O, W) { \
    float t0[8], t1[8], t2[8], t3[8]; \
    h8f(*(const H8*)(pin + (O).x + ch), t0); \
    h8f(*(const H8*)(pin + (O).y + ch), t1); \
    h8f(*(const H8*)(pin + (O).z + ch), t2); \
    h8f(*(const H8*)(pin + (O).w + ch), t3); \
    _Pragma("unroll") \
    for (int i = 0; i < 8; i++) \
      a2[i] += (W).x * t0[i] + (W).y * t1[i] + (W).z * t2[i] + (W).w * t3[i]; }
  GRP(c.o0, c.w0)
  GRP(c.o1, c.w1)
  GRP(c.o2, c.w2)
  GRP(c.o3, c.w3)
#undef GRP
  *(H8*)(outb + cb + rowel) = f8h(a2);
  if (ACC == 1) {
    float af[8];
    h8f(*(const H8*)(accAdd + cb + rowel), af);
#pragma unroll
    for (int i = 0; i < 8; i++) af[i] += a2[i];
    *(H8*)(accOut + cb + rowel) = f8h(af);
  } else if (ACC == 2) {
    float af[8];
    h8f(*(const H8*)(accOut + cb + rowel), af);
#pragma unroll
    for (int i = 0; i < 8; i++) af[i] += a2[i];
    *(H8*)(accOut + cb + rowel) = f8h(af);
  }
}

// ---------------- final: out = sigmoid(m_own + S t + S^2 t)
__global__ __launch_bounds__(256) void fin_kernel(const __half* __restrict__ tb,
                                                  const __half* __restrict__ mb,
                                                  const uint4* __restrict__ c1tab,
                                                  const uint4* __restrict__ c2tab,
                                                  __half* __restrict__ outb) {
  __shared__ uint4 c2s[128];
  __shared__ uint4 c1s[32];
  int tid = threadIdx.x;
  int slot0 = slot_base_64k<16>(blockIdx.x);
  if (tid < 128) c2s[tid] = c2tab[(size_t)slot0 * 8 + tid];
  if (tid < 32)  c1s[tid] = c1tab[(size_t)slot0 * 2 + tid];
  __syncthreads();
  const CoefC c = ((const CoefC*)c2s)[tid >> 4];
  const Coef1 a = ((const Coef1*)c1s)[tid >> 4];
  int slot = slot0 + (tid >> 4);
  int ch = (tid & 15) << 3;
  int chain = slot >> 15;
  size_t cb = (size_t)chain * PC;
  const __half* pin = tb + cb;
  int rowel = ((slot & 32767) << 7) + ch;

  float r[8] = {};
#define GRP(O, W) { \
    float t0[8], t1[8], t2[8], t3[8]; \
    h8f(*(const H8*)(pin + (O).x + ch), t0); \
    h8f(*(const H8*)(pin + (O).y + ch), t1); \
    h8f(*(const H8*)(pin + (O).z + ch), t2); \
    h8f(*(const H8*)(pin + (O).w + ch), t3); \
    _Pragma("unroll") \
    for (int i = 0; i < 8; i++) \
      r[i] += (W).x * t0[i] + (W).y * t1[i] + (W).z * t2[i] + (W).w * t3[i]; }
  GRP(a.oa, a.wa)
  GRP(c.o0, c.w0)
  GRP(c.o1, c.w1)
  GRP(c.o2, c.w2)
  GRP(c.o3, c.w3)
#undef GRP
  float mf[8];
  h8f(*(const H8*)(mb + cb + rowel), mf);
#pragma unroll
  for (int i = 0; i < 8; i++) r[i] = sigf(mf[i] + r[i]);
  *(H8*)(outb + cb + rowel) = f8h(r);
}

// ---------------- depthwise 3x3, zero pad, XCD-local mapping
template <int C>
__global__ __launch_bounds__(256) void dw_kernel(const __half* __restrict__ in,
                                                 const float* __restrict__ wT,
                                                 __half* __restrict__ out) {
  int tid = threadIdx.x;
  constexpr int TPP = C / 8;
  constexpr int PPB = 256 / TPP;
  int slot = slot_base_32k<PPB>(blockIdx.x) + tid / TPP;
  int ch = (tid % TPP) * 8;
  int b = slot >> 14, h = (slot >> 7) & 127, w = slot & 127;
  const __half* src;
  int choff;
  if (C == 256) { src = in + ((ch < 128) ? 0 : (size_t)PC); choff = ch & 127; }
  else          { src = in; choff = ch; }
  float acc[8] = {};
#pragma unroll
  for (int t = 0; t < 9; t++) {
    int dy = t / 3 - 1, dx = t % 3 - 1;
    int yy = h + dy, xx = w + dx;
    if (yy < 0 || yy > 127 || xx < 0 || xx > 127) continue;
    int q = (b << 14) + yy * 128 + xx;
    float v[8];
    h8f(*(const H8*)(src + (size_t)q * 128 + choff), v);
    float4 wa = *(const float4*)(wT + t * C + ch);
    float4 wb = *(const float4*)(wT + t * C + ch + 4);
    acc[0] = fmaf(wa.x, v[0], acc[0]);
    acc[1] = fmaf(wa.y, v[1], acc[1]);
    acc[2] = fmaf(wa.z, v[2], acc[2]);
    acc[3] = fmaf(wa.w, v[3], acc[3]);
    acc[4] = fmaf(wb.x, v[4], acc[4]);
    acc[5] = fmaf(wb.y, v[5], acc[5]);
    acc[6] = fmaf(wb.z, v[6], acc[6]);
    acc[7] = fmaf(wb.w, v[7], acc[7]);
  }
  *(H8*)(out + (size_t)slot * C + ch) = f8h(acc);
}

// ---------------- pw1: [P]x[256] @ w[128co][256ci] -> fp16 channels-last [P][128]
__global__ __launch_bounds__(256) void pw1_kernel(const __half* __restrict__ in,
                                                  const __half* __restrict__ w16,
                                                  const float* __restrict__ bias,
                                                  __half* __restrict__ out) {
  int tid = threadIdx.x;
  int p0 = blockIdx.x * 64;
  int wv = tid >> 6, ln = tid & 63;
  int hi = ln >> 4, lo = ln & 15;
  int px = p0 + wv * 16 + lo;
  f32x4 acc[8] = {};
  for (int k = 0; k < 256; k += 32) {
    f16x8 bF = *(const f16x8*)(in + (size_t)px * 256 + k + hi * 8);
#pragma unroll
    for (int m = 0; m < 8; m++) {
      f16x8 aF = *(const f16x8*)(w16 + (size_t)(m * 16 + lo) * 256 + k + hi * 8);
      acc[m] = __builtin_amdgcn_mfma_f32_16x16x32_f16(aF, bF, acc[m], 0, 0, 0);
    }
  }
  int opx = p0 + wv * 16 + lo;
#pragma unroll
  for (int m = 0; m < 8; m++) {
    int co = m * 16 + hi * 4;
    float4 bv = *(const float4*)(bias + co);
    H4 hv;
    hv.h[0] = __floats2half2_rn(acc[m][0] + bv.x, acc[m][1] + bv.y);
    hv.h[1] = __floats2half2_rn(acc[m][2] + bv.z, acc[m][3] + bv.w);
    *(H4*)(out + (size_t)opx * 128 + co) = hv;
  }
}

// ---------------- pw2: [P]x[128] @ w[128co][128ci] -> f32 NCHW + bias
__global__ __launch_bounds__(256) void pw2_kernel(const __half* __restrict__ in,
                                                  const __half* __restrict__ w16,
                                                  const float* __restrict__ bias,
                                                  float* __restrict__ out) {
  int tid = threadIdx.x;
  int p0 = blockIdx.x * 64;
  int b = p0 >> 14;
  int hw0 = p0 & 16383;
  int wv = tid >> 6, ln = tid & 63;
  int hi = ln >> 4, lo = ln & 15;
  int co0 = wv * 32;
  f32x4 acc[4][2] = {};
  for (int k = 0; k < 128; k += 32) {
    f16x8 aF[4], bF[2];
#pragma unroll
    for (int m = 0; m < 4; m++)
      aF[m] = *(const f16x8*)(in + (size_t)(p0 + m * 16 + lo) * 128 + k + hi * 8);
#pragma unroll
    for (int n = 0; n < 2; n++)
      bF[n] = *(const f16x8*)(w16 + (size_t)(co0 + n * 16 + lo) * 128 + k + hi * 8);
#pragma unroll
    for (int m = 0; m < 4; m++)
#pragma unroll
      for (int n = 0; n < 2; n++)
        acc[m][n] = __builtin_amdgcn_mfma_f32_16x16x32_f16(aF[m], bF[n], acc[m][n], 0, 0, 0);
  }
#pragma unroll
  for (int m = 0; m < 4; m++)
#pragma unroll
    for (int n = 0; n < 2; n++) {
      int co = co0 + n * 16 + lo;
      float bb = bias[co];
      float4 v = {acc[m][n][0] + bb, acc[m][n][1] + bb, acc[m][n][2] + bb, acc[m][n][3] + bb};
      *(float4*)(out + (size_t)(b * 128 + co) * HW + hw0 + m * 16 + hi * 4) = v;
    }
}

extern "C" void kernel_launch(void* const* d_in, const int* in_sizes, int n_in,
                              void* d_out, int out_size, void* d_ws, size_t ws_size,
                              hipStream_t stream) {
  const float* x     = (const float*)d_in[0];
  const float* grads = (const float*)d_in[1];
  const float* w1    = (const float*)d_in[2];
  const float* w2    = (const float*)d_in[3];
  const float* mdw   = (const float*)d_in[4];
  const float* mpw   = (const float*)d_in[5];
  const float* mb    = (const float*)d_in[6];
  const float* pdw   = (const float*)d_in[7];
  const float* ppw   = (const float*)d_in[8];
  const float* pb    = (const float*)d_in[9];
  float* out = (float*)d_out;
  char* wsb = (char*)d_ws;

  __half* M  = (__half*)wsb;
  __half* A  = (__half*)(wsb + (size_t)16777216);
  __half* Bb = (__half*)(wsb + (size_t)33554432);
  __half* Pb = (__half*)(wsb + (size_t)50331648);
  __half* Qb = (__half*)(wsb + (size_t)67108864);
  CoefC* C2  = (CoefC*)(wsb + (size_t)83886080);
  Coef1* C1  = (Coef1*)(wsb + (size_t)92274688);
  __half* WT16 = (__half*)(wsb + (size_t)94371840);
  __half* WPW1 = (__half*)(wsb + (size_t)94502912);
  __half* WPW2 = (__half*)(wsb + (size_t)94568448);
  float* wdwT  = (float*)(wsb + (size_t)94601216);
  float* pdwT  = wdwT + 2304;

  const uint4* c2u = (const uint4*)C2;
  const uint4* c1u = (const uint4*)C1;

  coef2_kernel<<<256, 256, 0, stream>>>(grads, C1, C2);
  tw_kernel<<<462, 256, 0, stream>>>(mdw, pdw, w1, w2, mpw, ppw, wdwT, pdwT, WT16, WPW1, WPW2);
  conv1_kernel<<<512, 256, 0, stream>>>(x, WT16, M);

  // p = (I + S^8 + S^16) m   (P buffer)
  s2_kernel<0><<<4096, 256, 0, stream>>>(M,  A,  nullptr, nullptr, c2u);   // S^2 m
  s2_kernel<0><<<4096, 256, 0, stream>>>(A,  Bb, nullptr, nullptr, c2u);   // S^4
  s2_kernel<0><<<4096, 256, 0, stream>>>(Bb, A,  nullptr, nullptr, c2u);   // S^6
  s2_kernel<1><<<4096, 256, 0, stream>>>(A,  Bb, M,       Pb,      c2u);   // S^8 ; P=m+S^8m
  s2_kernel<0><<<4096, 256, 0, stream>>>(Bb, A,  nullptr, nullptr, c2u);   // S^10
  s2_kernel<0><<<4096, 256, 0, stream>>>(A,  Bb, nullptr, nullptr, c2u);   // S^12
  s2_kernel<0><<<4096, 256, 0, stream>>>(Bb, A,  nullptr, nullptr, c2u);   // S^14
  s2_kernel<2><<<4096, 256, 0, stream>>>(A,  Bb, nullptr, Pb,      c2u);   // S^16 ; P+=S^16m
  // q = (I + S^4) p ; t = (I + S^2) q
  s2_kernel<0><<<4096, 256, 0, stream>>>(Pb, A,  nullptr, nullptr, c2u);   // S^2 p
  s2_kernel<1><<<4096, 256, 0, stream>>>(A,  Bb, Pb,      Qb,      c2u);   // S^4 p ; Q=p+S^4p
  s2_kernel<1><<<4096, 256, 0, stream>>>(Qb, A,  Qb,      Pb,      c2u);   // S^2 q ; T=q+S^2q
  // s = sigmoid(m + (S + S^2) t) -> A
  fin_kernel<<<4096, 256, 0, stream>>>(Pb, M, c1u, c2u, A);

  // merge stage
  __half* DW1 = Bb;
  __half* PW1 = Qb;
  __half* DW2 = Qb + PC;
  dw_kernel<256><<<4096, 256, 0, stream>>>(A, wdwT, DW1);
  pw1_kernel<<<512, 256, 0, stream>>>(DW1, WPW1, mb, PW1);
  dw_kernel<128><<<2048, 256, 0, stream>>>(PW1, pdwT, DW2);
  pw2_kernel<<<512, 256, 0, stream>>>(DW2, WPW2, pb, out);
}

// Round 7
// 268.186 us; speedup vs baseline: 2.7807x; 1.0576x over previous
//
#include <hip/hip_runtime.h>
#include <hip/hip_fp16.h>

// FlowLayer: B=2, CIN=256, COUT=128, H=W=128, iters=24.
// s = sum_{k=0..24} S^k m  =  m + (S+S^2) t,   t = (I+S^2)(I+S^4)(I+S^8+S^16) m
// 11 x S^2 (16-tap) + 1 final 20-tap kernel. XCD-aware block->slot mapping.
// This round: software-pipelined tap loads (8 in flight) + v_fma_mix f16->f32 FMAs.

#define PC 4194304
#define HW 16384

struct CoefC { int4 o0; float4 w0; int4 o1; float4 w1; int4 o2; float4 w2; int4 o3; float4 w3; };
struct Coef1 { int4 oa; float4 wa; };

struct alignas(16) H8 { __half2 h[4]; };
struct alignas(8)  H4 { __half2 h[2]; };
typedef _Float16 f16x8 __attribute__((ext_vector_type(8)));
typedef float f32x4 __attribute__((ext_vector_type(4)));

__device__ __forceinline__ float sigf(float v) { return 1.0f / (1.0f + __expf(-v)); }

__device__ __forceinline__ H8 f8h(const float* f) {
  H8 r;
#pragma unroll
  for (int i = 0; i < 4; i++) r.h[i] = __floats2half2_rn(f[2*i], f[2*i+1]);
  return r;
}
__device__ __forceinline__ f16x8 ld8(const __half* p) { return *(const f16x8*)p; }
__device__ __forceinline__ void fma8(float* a, const f16x8& v, float w) {
#pragma unroll
  for (int i = 0; i < 8; i++) a[i] = fmaf(w, (float)v[i], a[i]);   // v_fma_mix
}

// XCD-aware slot base (65536-slot space: 2 chains x 2 batches = 4 images of 16384).
template <int SPB>
__device__ __forceinline__ int slot_base_64k(int bid) {
  int xcd = bid & 7;
  int i = xcd >> 1;
  int half = xcd & 1;
  int sub = bid >> 3;
  return (i >> 1) * 32768 + (i & 1) * 16384 + half * 8192 + sub * SPB;
}
// 32768-slot space (2 batches): image b -> 4 XCDs, each a quarter-image.
template <int SPB>
__device__ __forceinline__ int slot_base_32k(int bid) {
  int xcd = bid & 7;
  int b = xcd >> 2;
  int q = xcd & 3;
  int sub = bid >> 3;
  return b * 16384 + q * 4096 + sub * SPB;
}

// ---------------- per-pixel bilinear stencil
__device__ __forceinline__ void stencil(const float* __restrict__ g, float sgn, int pix,
                                        int4& op, float4& wt) {
  int b = pix >> 14, hw = pix & 16383;
  int h = hw >> 7, w = hw & 127;
  float gx = g[(size_t)(b * 2 + 0) * HW + hw];
  float gy = g[(size_t)(b * 2 + 1) * HW + hw];
  float xp = (float)w + sgn * gx;
  float yp = (float)h + sgn * gy;
  float x0f = floorf(xp), y0f = floorf(yp);
  float fx = xp - x0f, fy = yp - y0f;
  int x0 = (int)x0f, y0 = (int)y0f;
  int x1 = x0 + 1, y1 = y0 + 1;
  bool vx0 = (x0 >= 0) && (x0 <= 127);
  bool vx1 = (x1 >= 0) && (x1 <= 127);
  bool vy0 = (y0 >= 0) && (y0 <= 127);
  bool vy1 = (y1 >= 0) && (y1 <= 127);
  int x0c = min(max(x0, 0), 127), x1c = min(max(x1, 0), 127);
  int y0c = min(max(y0, 0), 127), y1c = min(max(y1, 0), 127);
  int bb = b << 14;
  op.x = bb + y0c * 128 + x0c;
  op.y = bb + y0c * 128 + x1c;
  op.z = bb + y1c * 128 + x0c;
  op.w = bb + y1c * 128 + x1c;
  wt.x = (vx0 && vy0) ? (1.f - fx) * (1.f - fy) : 0.f;
  wt.y = (vx1 && vy0) ? fx * (1.f - fy) : 0.f;
  wt.z = (vx0 && vy1) ? (1.f - fx) * fy : 0.f;
  wt.w = (vx1 && vy1) ? fx * fy : 0.f;
}

__device__ __forceinline__ int4 shl7(int4 v) {
  return make_int4(v.x << 7, v.y << 7, v.z << 7, v.w << 7);
}
__device__ __forceinline__ float4 scale4(float4 v, float s) {
  return make_float4(v.x * s, v.y * s, v.z * s, v.w * s);
}

// ---------------- merged prep: stencil tables (bid<256) + weight conversions (bid>=256)
__global__ __launch_bounds__(256) void prep_kernel(const float* __restrict__ grads,
                                                   Coef1* __restrict__ c1,
                                                   CoefC* __restrict__ c2,
                                                   const float* __restrict__ mdw,
                                                   const float* __restrict__ pdw,
                                                   const float* __restrict__ w1,
                                                   const float* __restrict__ w2,
                                                   const float* __restrict__ mpw,
                                                   const float* __restrict__ ppw,
                                                   float* __restrict__ wdwT,
                                                   float* __restrict__ pdwT,
                                                   __half* __restrict__ wT16,
                                                   __half* __restrict__ wpw1,
                                                   __half* __restrict__ wpw2) {
  int bid = blockIdx.x;
  int tid = threadIdx.x;
  if (bid < 256) {
    int idx = bid * 256 + tid;
    int chain = idx >> 15;
    int p = idx & 32767;
    float sgn = chain ? -3.96875f : 3.96875f;   // 63.5*1.5/24
    int4 op; float4 ow;
    stencil(grads, sgn, p, op, ow);
    Coef1 a; a.oa = shl7(op); a.wa = ow;
    c1[idx] = a;
    CoefC c;
    int4 o2; float4 nw;
    stencil(grads, sgn, op.x, o2, nw); c.o0 = shl7(o2); c.w0 = scale4(nw, ow.x);
    stencil(grads, sgn, op.y, o2, nw); c.o1 = shl7(o2); c.w1 = scale4(nw, ow.y);
    stencil(grads, sgn, op.z, o2, nw); c.o2 = shl7(o2); c.w2 = scale4(nw, ow.z);
    stencil(grads, sgn, op.w, o2, nw); c.o3 = shl7(o2); c.w3 = scale4(nw, ow.w);
    c2[idx] = c;
  } else {
    int i = (bid - 256) * 256 + tid;
    if (i < 65536) {
      int co = i >> 8, ci = i & 255;
      float v = (co < 128) ? w1[co * 256 + ci] : w2[(size_t)(co - 128) * 256 + ci];
      wT16[i] = __float2half(v);
    } else if (i < 98304) {
      int j = i - 65536;
      wpw1[j] = __float2half(mpw[j]);
    } else if (i < 114688) {
      int j = i - 98304;
      wpw2[j] = __float2half(ppw[j]);
    } else if (i < 116992) {
      int j = i - 114688;
      int ch = j / 9, t = j % 9;
      wdwT[t * 256 + ch] = mdw[j];
    } else if (i < 118144) {
      int j = i - 116992;
      int ch = j / 9, t = j % 9;
      pdwT[t * 128 + ch] = pdw[j];
    }
  }
}

// ---------------- conv1x1 via f16 MFMA
__global__ __launch_bounds__(256) void conv1_kernel(const float* __restrict__ x,
                                                    const __half* __restrict__ wT16,
                                                    __half* __restrict__ mOut) {
  __shared__ __align__(16) char As[4096];
  __shared__ __align__(16) char Bs[16384];
  int tid = threadIdx.x;
  int p0 = blockIdx.x * 64;
  int b = p0 >> 14;
  int hw0 = p0 & 16383;
  int wv = tid >> 6, ln = tid & 63;
  int hi = ln >> 4, lo = ln & 15;
  f32x4 acc[4][4] = {};
  const float* xb = x + (size_t)b * 256 * HW + hw0;
  int apx = tid & 63, ac8 = (tid >> 6) * 8;
  int abyte = (apx * 64 + ac8 * 2) ^ ((apx & 3) << 4);
  for (int k = 0; k < 256; k += 32) {
    f16x8 av;
#pragma unroll
    for (int j = 0; j < 8; j++) av[j] = (_Float16)xb[(size_t)(k + ac8 + j) * HW + apx];
    if (k) __syncthreads();
    *(f16x8*)(As + abyte) = av;
    {
      const __half* src = wT16 + (size_t)tid * 256 + k;
#pragma unroll
      for (int s = 0; s < 4; s++) {
        f16x8 bv = *(const f16x8*)(src + s * 8);
        int byte = (tid * 64 + s * 16) ^ ((tid & 3) << 4);
        *(f16x8*)(Bs + byte) = bv;
      }
    }
    __syncthreads();
    f16x8 aF[4], bF[4];
#pragma unroll
    for (int m = 0; m < 4; m++) {
      int px = m * 16 + lo;
      int byte = (px * 64 + hi * 16) ^ ((px & 3) << 4);
      aF[m] = *(const f16x8*)(As + byte);
    }
#pragma unroll
    for (int n = 0; n < 4; n++) {
      int co = wv * 64 + n * 16 + lo;
      int byte = (co * 64 + hi * 16) ^ ((co & 3) << 4);
      bF[n] = *(const f16x8*)(Bs + byte);
    }
#pragma unroll
    for (int m = 0; m < 4; m++)
#pragma unroll
      for (int n = 0; n < 4; n++)
        acc[m][n] = __builtin_amdgcn_mfma_f32_16x16x32_f16(aF[m], bF[n], acc[m][n], 0, 0, 0);
  }
  size_t base = (wv >= 2) ? (size_t)PC : 0;
  int col0 = (wv & 1) * 64;
#pragma unroll
  for (int m = 0; m < 4; m++)
#pragma unroll
    for (int n = 0; n < 4; n++) {
      int col = col0 + n * 16 + lo;
#pragma unroll
      for (int rr = 0; rr < 4; rr++) {
        int px = p0 + m * 16 + hi * 4 + rr;
        mOut[base + (size_t)px * 128 + col] = __float2half(sigf(acc[m][n][rr]));
      }
    }
}

// ---------------- S^2 (16 taps), pipelined loads (8 in flight), fma_mix
template <int ACC>
__global__ __launch_bounds__(256) void s2_kernel(const __half* __restrict__ inb,
                                                 __half* __restrict__ outb,
                                                 const __half* __restrict__ accAdd,
                                                 __half* __restrict__ accOut,
                                                 const uint4* __restrict__ c2tab) {
  __shared__ uint4 cs[128];
  int tid = threadIdx.x;
  int slot0 = slot_base_64k<16>(blockIdx.x);
  if (tid < 128) cs[tid] = c2tab[(size_t)slot0 * 8 + tid];
  __syncthreads();
  const CoefC c = ((const CoefC*)cs)[tid >> 4];
  int slot = slot0 + (tid >> 4);
  int ch = (tid & 15) << 3;
  int chain = slot >> 15;
  size_t cb = (size_t)chain * PC;
  const __half* base = inb + cb + ch;
  int rowel = ((slot & 32767) << 7) + ch;

  float a2[8] = {};
  f16x8 p0 = ld8(base + c.o0.x), p1 = ld8(base + c.o0.y),
        p2 = ld8(base + c.o0.z), p3 = ld8(base + c.o0.w);
  f16x8 q0 = ld8(base + c.o1.x), q1 = ld8(base + c.o1.y),
        q2 = ld8(base + c.o1.z), q3 = ld8(base + c.o1.w);
  fma8(a2, p0, c.w0.x); fma8(a2, p1, c.w0.y); fma8(a2, p2, c.w0.z); fma8(a2, p3, c.w0.w);
  p0 = ld8(base + c.o2.x); p1 = ld8(base + c.o2.y);
  p2 = ld8(base + c.o2.z); p3 = ld8(base + c.o2.w);
  fma8(a2, q0, c.w1.x); fma8(a2, q1, c.w1.y); fma8(a2, q2, c.w1.z); fma8(a2, q3, c.w1.w);
  q0 = ld8(base + c.o3.x); q1 = ld8(base + c.o3.y);
  q2 = ld8(base + c.o3.z); q3 = ld8(base + c.o3.w);
  fma8(a2, p0, c.w2.x); fma8(a2, p1, c.w2.y); fma8(a2, p2, c.w2.z); fma8(a2, p3, c.w2.w);
  fma8(a2, q0, c.w3.x); fma8(a2, q1, c.w3.y); fma8(a2, q2, c.w3.z); fma8(a2, q3, c.w3.w);

  *(H8*)(outb + cb + rowel) = f8h(a2);
  if (ACC == 1) {
    f16x8 av = ld8(accAdd + cb + rowel);
    float af[8];
#pragma unroll
    for (int i = 0; i < 8; i++) af[i] = a2[i] + (float)av[i];
    *(H8*)(accOut + cb + rowel) = f8h(af);
  } else if (ACC == 2) {
    f16x8 av = ld8(accOut + cb + rowel);
    float af[8];
#pragma unroll
    for (int i = 0; i < 8; i++) af[i] = a2[i] + (float)av[i];
    *(H8*)(accOut + cb + rowel) = f8h(af);
  }
}

// ---------------- final: out = sigmoid(m_own + S t + S^2 t)  (20 taps), pipelined
__global__ __launch_bounds__(256) void fin_kernel(const __half* __restrict__ tb,
                                                  const __half* __restrict__ mb,
                                                  const uint4* __restrict__ c1tab,
                                                  const uint4* __restrict__ c2tab,
                                                  __half* __restrict__ outb) {
  __shared__ uint4 c2s[128];
  __shared__ uint4 c1s[32];
  int tid = threadIdx.x;
  int slot0 = slot_base_64k<16>(blockIdx.x);
  if (tid < 128) c2s[tid] = c2tab[(size_t)slot0 * 8 + tid];
  if (tid < 32)  c1s[tid] = c1tab[(size_t)slot0 * 2 + tid];
  __syncthreads();
  const CoefC c = ((const CoefC*)c2s)[tid >> 4];
  const Coef1 a = ((const Coef1*)c1s)[tid >> 4];
  int slot = slot0 + (tid >> 4);
  int ch = (tid & 15) << 3;
  int chain = slot >> 15;
  size_t cb = (size_t)chain * PC;
  const __half* base = tb + cb + ch;
  int rowel = ((slot & 32767) << 7) + ch;

  float r[8] = {};
  f16x8 p0 = ld8(base + a.oa.x), p1 = ld8(base + a.oa.y),
        p2 = ld8(base + a.oa.z), p3 = ld8(base + a.oa.w);
  f16x8 q0 = ld8(base + c.o0.x), q1 = ld8(base + c.o0.y),
        q2 = ld8(base + c.o0.z), q3 = ld8(base + c.o0.w);
  fma8(r, p0, a.wa.x); fma8(r, p1, a.wa.y); fma8(r, p2, a.wa.z); fma8(r, p3, a.wa.w);
  p0 = ld8(base + c.o1.x); p1 = ld8(base + c.o1.y);
  p2 = ld8(base + c.o1.z); p3 = ld8(base + c.o1.w);
  fma8(r, q0, c.w0.x); fma8(r, q1, c.w0.y); fma8(r, q2, c.w0.z); fma8(r, q3, c.w0.w);
  q0 = ld8(base + c.o2.x); q1 = ld8(base + c.o2.y);
  q2 = ld8(base + c.o2.z); q3 = ld8(base + c.o2.w);
  fma8(r, p0, c.w1.x); fma8(r, p1, c.w1.y); fma8(r, p2, c.w1.z); fma8(r, p3, c.w1.w);
  p0 = ld8(base + c.o3.x); p1 = ld8(base + c.o3.y);
  p2 = ld8(base + c.o3.z); p3 = ld8(base + c.o3.w);
  fma8(r, q0, c.w2.x); fma8(r, q1, c.w2.y); fma8(r, q2, c.w2.z); fma8(r, q3, c.w2.w);
  fma8(r, p0, c.w3.x); fma8(r, p1, c.w3.y); fma8(r, p2, c.w3.z); fma8(r, p3, c.w3.w);

  f16x8 mv = ld8(mb + cb + rowel);
#pragma unroll
  for (int i = 0; i < 8; i++) r[i] = sigf(r[i] + (float)mv[i]);
  *(H8*)(outb + cb + rowel) = f8h(r);
}

// ---------------- depthwise 3x3, zero pad, XCD-local mapping, fma_mix
template <int C>
__global__ __launch_bounds__(256) void dw_kernel(const __half* __restrict__ in,
                                                 const float* __restrict__ wT,
                                                 __half* __restrict__ out) {
  int tid = threadIdx.x;
  constexpr int TPP = C / 8;
  constexpr int PPB = 256 / TPP;
  int slot = slot_base_32k<PPB>(blockIdx.x) + tid / TPP;
  int ch = (tid % TPP) * 8;
  int b = slot >> 14, h = (slot >> 7) & 127, w = slot & 127;
  const __half* src;
  int choff;
  if (C == 256) { src = in + ((ch < 128) ? 0 : (size_t)PC); choff = ch & 127; }
  else          { src = in; choff = ch; }
  float acc[8] = {};
#pragma unroll
  for (int t = 0; t < 9; t++) {
    int dy = t / 3 - 1, dx = t % 3 - 1;
    int yy = h + dy, xx = w + dx;
    if (yy < 0 || yy > 127 || xx < 0 || xx > 127) continue;
    int q = (b << 14) + yy * 128 + xx;
    f16x8 v = ld8(src + (size_t)q * 128 + choff);
    float4 wa = *(const float4*)(wT + t * C + ch);
    float4 wb = *(const float4*)(wT + t * C + ch + 4);
    acc[0] = fmaf(wa.x, (float)v[0], acc[0]);
    acc[1] = fmaf(wa.y, (float)v[1], acc[1]);
    acc[2] = fmaf(wa.z, (float)v[2], acc[2]);
    acc[3] = fmaf(wa.w, (float)v[3], acc[3]);
    acc[4] = fmaf(wb.x, (float)v[4], acc[4]);
    acc[5] = fmaf(wb.y, (float)v[5], acc[5]);
    acc[6] = fmaf(wb.z, (float)v[6], acc[6]);
    acc[7] = fmaf(wb.w, (float)v[7], acc[7]);
  }
  *(H8*)(out + (size_t)slot * C + ch) = f8h(acc);
}

// ---------------- pw1: [P]x[256] @ w[128co][256ci] -> fp16 channels-last [P][128]
__global__ __launch_bounds__(256) void pw1_kernel(const __half* __restrict__ in,
                                                  const __half* __restrict__ w16,
                                                  const float* __restrict__ bias,
                                                  __half* __restrict__ out) {
  int tid = threadIdx.x;
  int p0 = blockIdx.x * 64;
  int wv = tid >> 6, ln = tid & 63;
  int hi = ln >> 4, lo = ln & 15;
  int px = p0 + wv * 16 + lo;
  f32x4 acc[8] = {};
  for (int k = 0; k < 256; k += 32) {
    f16x8 bF = *(const f16x8*)(in + (size_t)px * 256 + k + hi * 8);
#pragma unroll
    for (int m = 0; m < 8; m++) {
      f16x8 aF = *(const f16x8*)(w16 + (size_t)(m * 16 + lo) * 256 + k + hi * 8);
      acc[m] = __builtin_amdgcn_mfma_f32_16x16x32_f16(aF, bF, acc[m], 0, 0, 0);
    }
  }
  int opx = p0 + wv * 16 + lo;
#pragma unroll
  for (int m = 0; m < 8; m++) {
    int co = m * 16 + hi * 4;
    float4 bv = *(const float4*)(bias + co);
    H4 hv;
    hv.h[0] = __floats2half2_rn(acc[m][0] + bv.x, acc[m][1] + bv.y);
    hv.h[1] = __floats2half2_rn(acc[m][2] + bv.z, acc[m][3] + bv.w);
    *(H4*)(out + (size_t)opx * 128 + co) = hv;
  }
}

// ---------------- pw2: [P]x[128] @ w[128co][128ci] -> f32 NCHW + bias
__global__ __launch_bounds__(256) void pw2_kernel(const __half* __restrict__ in,
                                                  const __half* __restrict__ w16,
                                                  const float* __restrict__ bias,
                                                  float* __restrict__ out) {
  int tid = threadIdx.x;
  int p0 = blockIdx.x * 64;
  int b = p0 >> 14;
  int hw0 = p0 & 16383;
  int wv = tid >> 6, ln = tid & 63;
  int hi = ln >> 4, lo = ln & 15;
  int co0 = wv * 32;
  f32x4 acc[4][2] = {};
  for (int k = 0; k < 128; k += 32) {
    f16x8 aF[4], bF[2];
#pragma unroll
    for (int m = 0; m < 4; m++)
      aF[m] = *(const f16x8*)(in + (size_t)(p0 + m * 16 + lo) * 128 + k + hi * 8);
#pragma unroll
    for (int n = 0; n < 2; n++)
      bF[n] = *(const f16x8*)(w16 + (size_t)(co0 + n * 16 + lo) * 128 + k + hi * 8);
#pragma unroll
    for (int m = 0; m < 4; m++)
#pragma unroll
      for (int n = 0; n < 2; n++)
        acc[m][n] = __builtin_amdgcn_mfma_f32_16x16x32_f16(aF[m], bF[n], acc[m][n], 0, 0, 0);
  }
#pragma unroll
  for (int m = 0; m < 4; m++)
#pragma unroll
    for (int n = 0; n < 2; n++) {
      int co = co0 + n * 16 + lo;
      float bb = bias[co];
      float4 v = {acc[m][n][0] + bb, acc[m][n][1] + bb, acc[m][n][2] + bb, acc[m][n][3] + bb};
      *(float4*)(out + (size_t)(b * 128 + co) * HW + hw0 + m * 16 + hi * 4) = v;
    }
}

extern "C" void kernel_launch(void* const* d_in, const int* in_sizes, int n_in,
                              void* d_out, int out_size, void* d_ws, size_t ws_size,
                              hipStream_t stream) {
  const float* x     = (const float*)d_in[0];
  const float* grads = (const float*)d_in[1];
  const float* w1    = (const float*)d_in[2];
  const float* w2    = (const float*)d_in[3];
  const float* mdw   = (const float*)d_in[4];
  const float* mpw   = (const float*)d_in[5];
  const float* mb    = (const float*)d_in[6];
  const float* pdw   = (const float*)d_in[7];
  const float* ppw   = (const float*)d_in[8];
  const float* pb    = (const float*)d_in[9];
  float* out = (float*)d_out;
  char* wsb = (char*)d_ws;

  __half* M  = (__half*)wsb;
  __half* A  = (__half*)(wsb + (size_t)16777216);
  __half* Bb = (__half*)(wsb + (size_t)33554432);
  __half* Pb = (__half*)(wsb + (size_t)50331648);
  __half* Qb = (__half*)(wsb + (size_t)67108864);
  CoefC* C2  = (CoefC*)(wsb + (size_t)83886080);
  Coef1* C1  = (Coef1*)(wsb + (size_t)92274688);
  __half* WT16 = (__half*)(wsb + (size_t)94371840);
  __half* WPW1 = (__half*)(wsb + (size_t)94502912);
  __half* WPW2 = (__half*)(wsb + (size_t)94568448);
  float* wdwT  = (float*)(wsb + (size_t)94601216);
  float* pdwT  = wdwT + 2304;

  const uint4* c2u = (const uint4*)C2;
  const uint4* c1u = (const uint4*)C1;

  prep_kernel<<<718, 256, 0, stream>>>(grads, C1, C2, mdw, pdw, w1, w2, mpw, ppw,
                                       wdwT, pdwT, WT16, WPW1, WPW2);
  conv1_kernel<<<512, 256, 0, stream>>>(x, WT16, M);

  // p = (I + S^8 + S^16) m   (P buffer)
  s2_kernel<0><<<4096, 256, 0, stream>>>(M,  A,  nullptr, nullptr, c2u);   // S^2 m
  s2_kernel<0><<<4096, 256, 0, stream>>>(A,  Bb, nullptr, nullptr, c2u);   // S^4
  s2_kernel<0><<<4096, 256, 0, stream>>>(Bb, A,  nullptr, nullptr, c2u);   // S^6
  s2_kernel<1><<<4096, 256, 0, stream>>>(A,  Bb, M,       Pb,      c2u);   // S^8 ; P=m+S^8m
  s2_kernel<0><<<4096, 256, 0, stream>>>(Bb, A,  nullptr, nullptr, c2u);   // S^10
  s2_kernel<0><<<4096, 256, 0, stream>>>(A,  Bb, nullptr, nullptr, c2u);   // S^12
  s2_kernel<0><<<4096, 256, 0, stream>>>(Bb, A,  nullptr, nullptr, c2u);   // S^14
  s2_kernel<2><<<4096, 256, 0, stream>>>(A,  Bb, nullptr, Pb,      c2u);   // S^16 ; P+=S^16m
  // q = (I + S^4) p ; t = (I + S^2) q
  s2_kernel<0><<<4096, 256, 0, stream>>>(Pb, A,  nullptr, nullptr, c2u);   // S^2 p
  s2_kernel<1><<<4096, 256, 0, stream>>>(A,  Bb, Pb,      Qb,      c2u);   // S^4 p ; Q=p+S^4p
  s2_kernel<1><<<4096, 256, 0, stream>>>(Qb, A,  Qb,      Pb,      c2u);   // S^2 q ; T=q+S^2q
  // s = sigmoid(m + (S + S^2) t) -> A
  fin_kernel<<<4096, 256, 0, stream>>>(Pb, M, c1u, c2u, A);

  // merge stage
  __half* DW1 = Bb;
  __half* PW1 = Qb;
  __half* DW2 = Qb + PC;
  dw_kernel<256><<<4096, 256, 0, stream>>>(A, wdwT, DW1);
  pw1_kernel<<<512, 256, 0, stream>>>(DW1, WPW1, mb, PW1);
  dw_kernel<128><<<2048, 256, 0, stream>>>(PW1, pdwT, DW2);
  pw2_kernel<<<512, 256, 0, stream>>>(DW2, WPW2, pb, out);
}